// Round 1
// baseline (614.800 us; speedup 1.0000x reference)
//
#include <hip/hip_runtime.h>
#include <hip/hip_bf16.h>
#include <cstdint>

// ---- problem constants ----
#define S_LEN  1024
#define DMODEL 1024
#define NTOK   4096   // B*S = 4*1024
#define NHEAD  16
#define HDIM   64
#define FFDIM  4096
#define NBATCH 4

using bf16x8 = __attribute__((ext_vector_type(8))) short;
using f32x4  = __attribute__((ext_vector_type(4))) float;

__device__ __forceinline__ ushort f2bf(float f) {
  union { float f; uint32_t u; } a; a.f = f;
  uint32_t u = a.u;
  u += 0x7FFFu + ((u >> 16) & 1u);   // RNE
  return (ushort)(u >> 16);
}
__device__ __forceinline__ float ld_as_float(const float* p, long i) { return p[i]; }
__device__ __forceinline__ float ld_as_float(const ushort* p, long i) {
  union { uint32_t u; float f; } c; c.u = ((uint32_t)p[i]) << 16; return c.f;
}
__device__ __forceinline__ void st_out(float* C, long i, float v) { C[i] = v; }
__device__ __forceinline__ void st_out(ushort* C, long i, float v) { C[i] = f2bf(v); }

// ---------------- LayerNorm (row of 1024 f32) -> bf16 ----------------
__global__ __launch_bounds__(256) void ln_kernel(const float* __restrict__ x,
    const float* __restrict__ g, const float* __restrict__ b,
    ushort* __restrict__ out) {
  int row = blockIdx.x;
  int tid = threadIdx.x;
  const float4* xr = (const float4*)(x + (long)row * DMODEL);
  float4 v = xr[tid];
  float s  = v.x + v.y + v.z + v.w;
  float s2 = v.x*v.x + v.y*v.y + v.z*v.z + v.w*v.w;
  for (int off = 32; off; off >>= 1) { s += __shfl_down(s, off); s2 += __shfl_down(s2, off); }
  __shared__ float red[8];
  int wid = tid >> 6, lane = tid & 63;
  if (lane == 0) { red[wid] = s; red[wid + 4] = s2; }
  __syncthreads();
  if (tid == 0) {
    red[0] = red[0] + red[1] + red[2] + red[3];
    red[4] = red[4] + red[5] + red[6] + red[7];
  }
  __syncthreads();
  float mu  = red[0] * (1.0f / DMODEL);
  float var = red[4] * (1.0f / DMODEL) - mu * mu;
  float rs  = rsqrtf(var + 1e-5f);
  float4 gg = ((const float4*)g)[tid];
  float4 bb = ((const float4*)b)[tid];
  ushort4 o;
  o.x = f2bf((v.x - mu) * rs * gg.x + bb.x);
  o.y = f2bf((v.y - mu) * rs * gg.y + bb.y);
  o.z = f2bf((v.z - mu) * rs * gg.z + bb.z);
  o.w = f2bf((v.w - mu) * rs * gg.w + bb.w);
  ((ushort4*)(out + (long)row * DMODEL))[tid] = o;
}

// ---------------- row softmax (1024 f32 -> bf16), scale 1/8 folded in ----------------
__global__ __launch_bounds__(256) void softmax_kernel(const float* __restrict__ scores,
                                                      ushort* __restrict__ p) {
  long row = blockIdx.x;
  int tid = threadIdx.x;
  const float4* sr = (const float4*)(scores + row * S_LEN);
  float4 v = sr[tid];
  float mx = fmaxf(fmaxf(v.x, v.y), fmaxf(v.z, v.w));
  for (int off = 32; off; off >>= 1) mx = fmaxf(mx, __shfl_xor(mx, off));
  __shared__ float red[8];
  int wid = tid >> 6, lane = tid & 63;
  if (lane == 0) red[wid] = mx;
  __syncthreads();
  if (tid == 0) red[0] = fmaxf(fmaxf(red[0], red[1]), fmaxf(red[2], red[3]));
  __syncthreads();
  mx = red[0];
  float4 e;
  e.x = expf((v.x - mx) * 0.125f);
  e.y = expf((v.y - mx) * 0.125f);
  e.z = expf((v.z - mx) * 0.125f);
  e.w = expf((v.w - mx) * 0.125f);
  float s = e.x + e.y + e.z + e.w;
  for (int off = 32; off; off >>= 1) s += __shfl_xor(s, off);
  __syncthreads();
  if (lane == 0) red[4 + wid] = s;
  __syncthreads();
  if (tid == 0) red[4] = red[4] + red[5] + red[6] + red[7];
  __syncthreads();
  float inv = 1.0f / red[4];
  ushort4 o;
  o.x = f2bf(e.x * inv); o.y = f2bf(e.y * inv);
  o.z = f2bf(e.z * inv); o.w = f2bf(e.w * inv);
  ((ushort4*)(p + row * S_LEN))[tid] = o;
}

// ---------------- transpose + convert to bf16 ----------------
// in: logical [R][C], row stride ldin (dtype TIN); out: [C][R] bf16, row stride ldout.
// per-z input offset = (z>>4)*inZhi + (z&15)*inZlo ; per-z output offset = z*outZ.
template <typename TIN>
__global__ __launch_bounds__(256) void transpose_cvt(const TIN* __restrict__ in,
    ushort* __restrict__ out, int ldin, int ldout,
    long inZhi, long inZlo, long outZ) {
  int z = blockIdx.z;
  in  += (long)(z >> 4) * inZhi + (long)(z & 15) * inZlo;
  out += (long)z * outZ;
  __shared__ float tile[32][33];
  int c0 = blockIdx.x * 32, r0 = blockIdx.y * 32;
  int tx = threadIdx.x, ty = threadIdx.y;
  for (int i = ty; i < 32; i += 8)
    tile[i][tx] = ld_as_float(in, (long)(r0 + i) * ldin + c0 + tx);
  __syncthreads();
  for (int i = ty; i < 32; i += 8)
    out[(long)(c0 + i) * ldout + r0 + tx] = f2bf(tile[tx][i]);
}

// ---------------- bf16 MFMA GEMM:  C[n,m] = sum_k A[n,k]*BT[m,k] (+bias(+res))(gelu) ----
// 128x128 tile, BK=64, 4 waves (2x2), 16x16x32 bf16 MFMA. N%128==0, K%64==0; M guarded.
template <int ACT, bool BIAS, bool RES, typename TOUT>
__global__ __launch_bounds__(256) void gemm_bt(
    const ushort* __restrict__ A, const ushort* __restrict__ BT, TOUT* __restrict__ C,
    const float* __restrict__ bias, const float* __restrict__ resp,
    int M, int K, int lda, int ldb, int ldc,
    long aZ, long bZ, long cZ) {
  __shared__ __align__(16) ushort lA[128 * 72];
  __shared__ __align__(16) ushort lB[128 * 72];
  int z = blockIdx.z;
  A  += (long)z * aZ;
  BT += (long)z * bZ;
  long coff = (long)z * cZ;
  int n0 = blockIdx.y * 128, m0 = blockIdx.x * 128;
  int tid = threadIdx.x, lane = tid & 63, wid = tid >> 6;
  int wr = wid >> 1, wc = wid & 1;
  f32x4 acc[4][4];
#pragma unroll
  for (int i = 0; i < 4; i++)
#pragma unroll
    for (int j = 0; j < 4; j++) acc[i][j] = (f32x4){0.f, 0.f, 0.f, 0.f};

  int Mm1 = M - 1;
  int nK = K >> 6;
  for (int kt = 0; kt < nK; ++kt) {
#pragma unroll
    for (int r = 0; r < 4; ++r) {
      int chunk = r * 256 + tid;
      int row = chunk >> 3;
      int k0 = (chunk & 7) << 3;
      uint4 va = *(const uint4*)(A + (long)(n0 + row) * lda + kt * 64 + k0);
      *(uint4*)(&lA[row * 72 + k0]) = va;
      int mrow = min(m0 + row, Mm1);
      uint4 vb = *(const uint4*)(BT + (long)mrow * ldb + kt * 64 + k0);
      *(uint4*)(&lB[row * 72 + k0]) = vb;
    }
    __syncthreads();
#pragma unroll
    for (int kk = 0; kk < 2; ++kk) {
      int kf = kk * 32 + (lane >> 4) * 8;
      bf16x8 af[4], bfr[4];
#pragma unroll
      for (int i = 0; i < 4; i++) {
        af[i]  = *(const bf16x8*)(&lA[(wr * 64 + i * 16 + (lane & 15)) * 72 + kf]);
        bfr[i] = *(const bf16x8*)(&lB[(wc * 64 + i * 16 + (lane & 15)) * 72 + kf]);
      }
#pragma unroll
      for (int i = 0; i < 4; i++)
#pragma unroll
        for (int j = 0; j < 4; j++)
          acc[i][j] = __builtin_amdgcn_mfma_f32_16x16x32_bf16(af[i], bfr[j], acc[i][j], 0, 0, 0);
    }
    __syncthreads();
  }
  // epilogue
#pragma unroll
  for (int i = 0; i < 4; i++) {
    int rbase = n0 + wr * 64 + i * 16 + ((lane >> 4) << 2);
#pragma unroll
    for (int j = 0; j < 4; j++) {
      int col = m0 + wc * 64 + j * 16 + (lane & 15);
      if (col < M) {
        float bv = BIAS ? bias[col] : 0.0f;
#pragma unroll
        for (int q = 0; q < 4; q++) {
          int rowg = rbase + q;
          float vv = acc[i][j][q] + bv;
          if (ACT == 1) vv = 0.5f * vv * (1.0f + erff(vv * 0.70710678118f));
          long idx = coff + (long)rowg * ldc + col;
          if (RES) vv += resp[idx];
          st_out(C, idx, vv);
        }
      }
    }
  }
}

// ---------------- host orchestration ----------------
extern "C" void kernel_launch(void* const* d_in, const int* in_sizes, int n_in,
                              void* d_out, int out_size, void* d_ws, size_t ws_size,
                              hipStream_t stream) {
  const float* x    = (const float*)d_in[0];
  const float* wq   = (const float*)d_in[1];
  const float* bq   = (const float*)d_in[2];
  const float* wk   = (const float*)d_in[3];
  const float* bk   = (const float*)d_in[4];
  const float* wv   = (const float*)d_in[5];
  const float* bv   = (const float*)d_in[6];
  const float* wo   = (const float*)d_in[7];
  const float* bo   = (const float*)d_in[8];
  const float* w1   = (const float*)d_in[9];
  const float* b1   = (const float*)d_in[10];
  const float* w2   = (const float*)d_in[11];
  const float* b2   = (const float*)d_in[12];
  const float* ln1g = (const float*)d_in[13];
  const float* ln1b = (const float*)d_in[14];
  const float* ln2g = (const float*)d_in[15];
  const float* ln2b = (const float*)d_in[16];
  float* out = (float*)d_out;

  char* ws = (char*)d_ws;
  size_t off = 0;
  auto alloc = [&](size_t bytes) { void* p = ws + off; off += (bytes + 255) & ~(size_t)255; return p; };
  ushort* h    = (ushort*)alloc((size_t)NTOK * DMODEL * 2);       // ln1 out; later ln2 out
  ushort* wqT  = (ushort*)alloc((size_t)DMODEL * DMODEL * 2);
  ushort* wkT  = (ushort*)alloc((size_t)DMODEL * DMODEL * 2);
  ushort* wvT  = (ushort*)alloc((size_t)DMODEL * DMODEL * 2);
  ushort* woT  = (ushort*)alloc((size_t)DMODEL * DMODEL * 2);
  ushort* w1T  = (ushort*)alloc((size_t)DMODEL * FFDIM * 2);      // [FF][D]
  ushort* w2T  = (ushort*)alloc((size_t)FFDIM * DMODEL * 2);      // [D][FF]
  ushort* qb   = (ushort*)alloc((size_t)NTOK * DMODEL * 2);
  ushort* kb   = (ushort*)alloc((size_t)NTOK * DMODEL * 2);
  ushort* vb   = (ushort*)alloc((size_t)NTOK * DMODEL * 2);
  ushort* vt   = (ushort*)alloc((size_t)64 * HDIM * S_LEN * 2);   // [bh][hd][s]
  ushort* attn = (ushort*)alloc((size_t)NTOK * DMODEL * 2);
  float*  scores = (float*)alloc((size_t)8 * S_LEN * S_LEN * 4);  // group of 8 heads
  ushort* P    = (ushort*)alloc((size_t)8 * S_LEN * S_LEN * 2);
  ushort* gact = (ushort*)scores;  // reuse (32MB == 32MB), scores dead by FFN time

  dim3 tb32(32, 8);
  // weight transposes (f32 -> bf16, [K][M] -> [M][K])
  hipLaunchKernelGGL((transpose_cvt<float>), dim3(DMODEL/32, DMODEL/32, 1), tb32, 0, stream,
                     wq, wqT, DMODEL, DMODEL, 0, 0, 0);
  hipLaunchKernelGGL((transpose_cvt<float>), dim3(DMODEL/32, DMODEL/32, 1), tb32, 0, stream,
                     wk, wkT, DMODEL, DMODEL, 0, 0, 0);
  hipLaunchKernelGGL((transpose_cvt<float>), dim3(DMODEL/32, DMODEL/32, 1), tb32, 0, stream,
                     wv, wvT, DMODEL, DMODEL, 0, 0, 0);
  hipLaunchKernelGGL((transpose_cvt<float>), dim3(DMODEL/32, DMODEL/32, 1), tb32, 0, stream,
                     wo, woT, DMODEL, DMODEL, 0, 0, 0);
  hipLaunchKernelGGL((transpose_cvt<float>), dim3(FFDIM/32, DMODEL/32, 1), tb32, 0, stream,
                     w1, w1T, FFDIM, DMODEL, 0, 0, 0);
  hipLaunchKernelGGL((transpose_cvt<float>), dim3(DMODEL/32, FFDIM/32, 1), tb32, 0, stream,
                     w2, w2T, DMODEL, FFDIM, 0, 0, 0);

  // LN1
  hipLaunchKernelGGL(ln_kernel, dim3(NTOK), dim3(256), 0, stream, x, ln1g, ln1b, h);

  // Q,K,V GEMMs: [4096,1024] = h @ W + b
  hipLaunchKernelGGL((gemm_bt<0, true, false, ushort>), dim3(8, 32, 1), dim3(256), 0, stream,
                     h, wqT, qb, bq, (const float*)nullptr,
                     DMODEL, DMODEL, DMODEL, DMODEL, DMODEL, 0L, 0L, 0L);
  hipLaunchKernelGGL((gemm_bt<0, true, false, ushort>), dim3(8, 32, 1), dim3(256), 0, stream,
                     h, wkT, kb, bk, (const float*)nullptr,
                     DMODEL, DMODEL, DMODEL, DMODEL, DMODEL, 0L, 0L, 0L);
  hipLaunchKernelGGL((gemm_bt<0, true, false, ushort>), dim3(8, 32, 1), dim3(256), 0, stream,
                     h, wvT, vb, bv, (const float*)nullptr,
                     DMODEL, DMODEL, DMODEL, DMODEL, DMODEL, 0L, 0L, 0L);

  // V transpose per (b,h): [s][hd] -> [hd][s]
  hipLaunchKernelGGL((transpose_cvt<ushort>), dim3(HDIM/32, S_LEN/32, 64), tb32, 0, stream,
                     vb, vt, DMODEL, S_LEN, (long)S_LEN * DMODEL, 64L, (long)HDIM * S_LEN);

  // attention in groups of 8 heads
  for (int g = 0; g < 8; ++g) {
    int bh0 = g * 8;
    int b = bh0 >> 4, h0 = bh0 & 15;
    const ushort* qbase = qb + (long)b * S_LEN * DMODEL + h0 * 64;
    const ushort* kbase = kb + (long)b * S_LEN * DMODEL + h0 * 64;
    // scores[z][sq][sk] = q . k  (unscaled; softmax applies 1/8)
    hipLaunchKernelGGL((gemm_bt<0, false, false, float>), dim3(8, 8, 8), dim3(256), 0, stream,
                       qbase, kbase, scores, (const float*)nullptr, (const float*)nullptr,
                       S_LEN, HDIM, DMODEL, DMODEL, S_LEN,
                       64L, 64L, (long)S_LEN * S_LEN);
    hipLaunchKernelGGL(softmax_kernel, dim3(8 * S_LEN), dim3(256), 0, stream, scores, P);
    // attn[b, sq, (h0+z)*64 + hd] = P @ V
    hipLaunchKernelGGL((gemm_bt<0, false, false, ushort>), dim3(1, 8, 8), dim3(256), 0, stream,
                       P, vt + (long)bh0 * HDIM * S_LEN,
                       attn + (long)b * S_LEN * DMODEL + h0 * 64,
                       (const float*)nullptr, (const float*)nullptr,
                       HDIM, S_LEN, S_LEN, S_LEN, DMODEL,
                       (long)S_LEN * S_LEN, (long)HDIM * S_LEN, 64L);
  }

  // x1 = x + attn @ wo + bo  -> d_out (f32)
  hipLaunchKernelGGL((gemm_bt<0, true, true, float>), dim3(8, 32, 1), dim3(256), 0, stream,
                     attn, woT, out, bo, x,
                     DMODEL, DMODEL, DMODEL, DMODEL, DMODEL, 0L, 0L, 0L);
  // LN2 on x1
  hipLaunchKernelGGL(ln_kernel, dim3(NTOK), dim3(256), 0, stream, out, ln2g, ln2b, h);
  // FFN1: gelu(h @ w1 + b1) -> gact bf16 [4096][4096]
  hipLaunchKernelGGL((gemm_bt<1, true, false, ushort>), dim3(32, 32, 1), dim3(256), 0, stream,
                     h, w1T, gact, b1, (const float*)nullptr,
                     FFDIM, DMODEL, DMODEL, DMODEL, FFDIM, 0L, 0L, 0L);
  // FFN2: out = x1 + gact @ w2 + b2  (residual = current d_out)
  hipLaunchKernelGGL((gemm_bt<0, true, true, float>), dim3(8, 32, 1), dim3(256), 0, stream,
                     gact, w2T, out, b2, out,
                     DMODEL, FFDIM, FFDIM, FFDIM, DMODEL, 0L, 0L, 0L);
  (void)in_sizes; (void)n_in; (void)out_size; (void)ws_size;
}

// Round 2
// 479.827 us; speedup vs baseline: 1.2813x; 1.2813x over previous
//
#include <hip/hip_runtime.h>
#include <hip/hip_bf16.h>
#include <cstdint>

// ---- problem constants ----
#define S_LEN  1024
#define DMODEL 1024
#define NTOK   4096   // B*S = 4*1024
#define NHEAD  16
#define HDIM   64
#define FFDIM  4096
#define NBATCH 4

using bf16x8 = __attribute__((ext_vector_type(8))) short;
using f32x4  = __attribute__((ext_vector_type(4))) float;

__device__ __forceinline__ ushort f2bf(float f) {
  union { float f; uint32_t u; } a; a.f = f;
  uint32_t u = a.u;
  u += 0x7FFFu + ((u >> 16) & 1u);   // RNE
  return (ushort)(u >> 16);
}
__device__ __forceinline__ float bf2f(ushort u) {
  union { uint32_t u; float f; } c; c.u = ((uint32_t)u) << 16; return c.f;
}
__device__ __forceinline__ float ld_as_float(const float* p, long i) { return p[i]; }
__device__ __forceinline__ float ld_as_float(const ushort* p, long i) { return bf2f(p[i]); }
__device__ __forceinline__ void st_out(float* C, long i, float v) { C[i] = v; }
__device__ __forceinline__ void st_out(ushort* C, long i, float v) { C[i] = f2bf(v); }

// async global->LDS, 16B per lane; LDS dest = wave-uniform base + lane*16
__device__ __forceinline__ void gld_lds16(const void* g, void* l) {
  __builtin_amdgcn_global_load_lds((const __attribute__((address_space(1))) void*)g,
                                   (__attribute__((address_space(3))) void*)l, 16, 0, 0);
}

// ---------------- LayerNorm (row of 1024 f32) -> bf16 ----------------
__global__ __launch_bounds__(256) void ln_kernel(const float* __restrict__ x,
    const float* __restrict__ g, const float* __restrict__ b,
    ushort* __restrict__ out) {
  int row = blockIdx.x;
  int tid = threadIdx.x;
  const float4* xr = (const float4*)(x + (long)row * DMODEL);
  float4 v = xr[tid];
  float s  = v.x + v.y + v.z + v.w;
  float s2 = v.x*v.x + v.y*v.y + v.z*v.z + v.w*v.w;
  for (int off = 32; off; off >>= 1) { s += __shfl_down(s, off); s2 += __shfl_down(s2, off); }
  __shared__ float red[8];
  int wid = tid >> 6, lane = tid & 63;
  if (lane == 0) { red[wid] = s; red[wid + 4] = s2; }
  __syncthreads();
  if (tid == 0) {
    red[0] = red[0] + red[1] + red[2] + red[3];
    red[4] = red[4] + red[5] + red[6] + red[7];
  }
  __syncthreads();
  float mu  = red[0] * (1.0f / DMODEL);
  float var = red[4] * (1.0f / DMODEL) - mu * mu;
  float rs  = rsqrtf(var + 1e-5f);
  float4 gg = ((const float4*)g)[tid];
  float4 bb = ((const float4*)b)[tid];
  ushort4 o;
  o.x = f2bf((v.x - mu) * rs * gg.x + bb.x);
  o.y = f2bf((v.y - mu) * rs * gg.y + bb.y);
  o.z = f2bf((v.z - mu) * rs * gg.z + bb.z);
  o.w = f2bf((v.w - mu) * rs * gg.w + bb.w);
  ((ushort4*)(out + (long)row * DMODEL))[tid] = o;
}

// ---------------- row softmax, bf16 in-place (1024 elems), scale 1/8 folded ----------------
__global__ __launch_bounds__(256) void softmax_bf16(ushort* __restrict__ sc) {
  long row = blockIdx.x;
  int tid = threadIdx.x;
  ushort4* rp = (ushort4*)(sc + row * S_LEN);
  ushort4 u = rp[tid];
  float4 v;
  v.x = bf2f(u.x); v.y = bf2f(u.y); v.z = bf2f(u.z); v.w = bf2f(u.w);
  float mx = fmaxf(fmaxf(v.x, v.y), fmaxf(v.z, v.w));
  for (int off = 32; off; off >>= 1) mx = fmaxf(mx, __shfl_xor(mx, off));
  __shared__ float red[8];
  int wid = tid >> 6, lane = tid & 63;
  if (lane == 0) red[wid] = mx;
  __syncthreads();
  if (tid == 0) red[0] = fmaxf(fmaxf(red[0], red[1]), fmaxf(red[2], red[3]));
  __syncthreads();
  mx = red[0];
  float4 e;
  e.x = expf((v.x - mx) * 0.125f);
  e.y = expf((v.y - mx) * 0.125f);
  e.z = expf((v.z - mx) * 0.125f);
  e.w = expf((v.w - mx) * 0.125f);
  float s = e.x + e.y + e.z + e.w;
  for (int off = 32; off; off >>= 1) s += __shfl_xor(s, off);
  if (lane == 0) red[4 + wid] = s;
  __syncthreads();
  if (tid == 0) red[4] = red[4] + red[5] + red[6] + red[7];
  __syncthreads();
  float inv = 1.0f / red[4];
  ushort4 o;
  o.x = f2bf(e.x * inv); o.y = f2bf(e.y * inv);
  o.z = f2bf(e.z * inv); o.w = f2bf(e.w * inv);
  rp[tid] = o;
}

// ---------------- transpose + convert to bf16 ----------------
// in: logical [R][C], row stride ldin (dtype TIN); out: [C][R] bf16, row stride ldout.
// per-z input offset = (z>>4)*inZhi + (z&15)*inZlo ; per-z output offset = z*outZ.
template <typename TIN>
__global__ __launch_bounds__(256) void transpose_cvt(const TIN* __restrict__ in,
    ushort* __restrict__ out, int ldin, int ldout,
    long inZhi, long inZlo, long outZ) {
  int z = blockIdx.z;
  in  += (long)(z >> 4) * inZhi + (long)(z & 15) * inZlo;
  out += (long)z * outZ;
  __shared__ float tile[32][33];
  int c0 = blockIdx.x * 32, r0 = blockIdx.y * 32;
  int tx = threadIdx.x, ty = threadIdx.y;
  for (int i = ty; i < 32; i += 8)
    tile[i][tx] = ld_as_float(in, (long)(r0 + i) * ldin + c0 + tx);
  __syncthreads();
  for (int i = ty; i < 32; i += 8)
    out[(long)(c0 + i) * ldout + r0 + tx] = f2bf(tile[tx][i]);
}

// ---------------- bf16 MFMA GEMM (m97 structure):  C[n,m] = A[n,:]·BT[m,:] ----------------
// 128x128 tile, BK=64, 4 waves (2x2), 16x16x32 bf16 MFMA, global_load_lds width-16,
// linear [128][64] LDS (global_load_lds requires linear dest). N%128==0, K%64==0; M guarded.
// per-z offsets: (z>>4)*Zhi + (z&15)*Zlo for A/B/C.
template <int ACT, bool BIAS, bool RES, typename TOUT>
__global__ __launch_bounds__(256) void gemm_bt(
    const ushort* __restrict__ A, const ushort* __restrict__ BT, TOUT* __restrict__ C,
    const float* __restrict__ bias, const float* __restrict__ resp,
    int M, int K, int lda, int ldb, int ldc,
    long aZhi, long aZlo, long bZhi, long bZlo, long cZhi, long cZlo) {
  __shared__ __align__(16) ushort lA[128 * 64];
  __shared__ __align__(16) ushort lB[128 * 64];
  int z = blockIdx.z;
  A  += (long)(z >> 4) * aZhi + (long)(z & 15) * aZlo;
  BT += (long)(z >> 4) * bZhi + (long)(z & 15) * bZlo;
  long coff = (long)(z >> 4) * cZhi + (long)(z & 15) * cZlo;
  int n0 = blockIdx.y * 128, m0 = blockIdx.x * 128;
  int tid = threadIdx.x, lane = tid & 63, wid = tid >> 6;
  int wr = wid >> 1, wc = wid & 1;
  int lrow = lane >> 3, lk = (lane & 7) << 3;
  f32x4 acc[4][4];
#pragma unroll
  for (int i = 0; i < 4; i++)
#pragma unroll
    for (int j = 0; j < 4; j++) acc[i][j] = (f32x4){0.f, 0.f, 0.f, 0.f};

  int Mm1 = M - 1;
  int nK = K >> 6;
  for (int kt = 0; kt < nK; ++kt) {
    const ushort* Ak = A + (kt << 6) + lk;
    const ushort* Bk = BT + (kt << 6) + lk;
#pragma unroll
    for (int c = 0; c < 4; ++c) {
      int ch = (wid << 2) | c;          // chunk 0..15 (8 rows each)
      int rb = (ch << 3) + lrow;        // row 0..127
      gld_lds16(Ak + (long)(n0 + rb) * lda, &lA[ch << 9]);
      int mrow = min(m0 + rb, Mm1);
      gld_lds16(Bk + (long)mrow * ldb, &lB[ch << 9]);
    }
    __syncthreads();   // compiler emits vmcnt(0) drain before barrier
#pragma unroll
    for (int kk = 0; kk < 2; ++kk) {
      int kf = (kk << 5) + ((lane >> 4) << 3);
      bf16x8 af[4], bfr[4];
#pragma unroll
      for (int i = 0; i < 4; i++) {
        af[i]  = *(const bf16x8*)(&lA[((wr << 6) + (i << 4) + (lane & 15)) * 64 + kf]);
        bfr[i] = *(const bf16x8*)(&lB[((wc << 6) + (i << 4) + (lane & 15)) * 64 + kf]);
      }
#pragma unroll
      for (int i = 0; i < 4; i++)
#pragma unroll
        for (int j = 0; j < 4; j++)
          acc[i][j] = __builtin_amdgcn_mfma_f32_16x16x32_bf16(af[i], bfr[j], acc[i][j], 0, 0, 0);
    }
    __syncthreads();
  }
  // epilogue: C/D layout col=lane&15, row=(lane>>4)*4+q  (m89/m91-verified)
#pragma unroll
  for (int i = 0; i < 4; i++) {
    int rbase = n0 + wr * 64 + i * 16 + ((lane >> 4) << 2);
#pragma unroll
    for (int j = 0; j < 4; j++) {
      int col = m0 + wc * 64 + j * 16 + (lane & 15);
      if (col < M) {
        float bv = BIAS ? bias[col] : 0.0f;
#pragma unroll
        for (int q = 0; q < 4; q++) {
          int rowg = rbase + q;
          float vv = acc[i][j][q] + bv;
          if (ACT == 1) vv = 0.5f * vv * (1.0f + erff(vv * 0.70710678118f));
          long idx = coff + (long)rowg * ldc + col;
          if (RES) vv += resp[idx];
          st_out(C, idx, vv);
        }
      }
    }
  }
}

// ---------------- host orchestration ----------------
extern "C" void kernel_launch(void* const* d_in, const int* in_sizes, int n_in,
                              void* d_out, int out_size, void* d_ws, size_t ws_size,
                              hipStream_t stream) {
  const float* x    = (const float*)d_in[0];
  const float* wq   = (const float*)d_in[1];
  const float* bq   = (const float*)d_in[2];
  const float* wk   = (const float*)d_in[3];
  const float* bk   = (const float*)d_in[4];
  const float* wv   = (const float*)d_in[5];
  const float* bv   = (const float*)d_in[6];
  const float* wo   = (const float*)d_in[7];
  const float* bo   = (const float*)d_in[8];
  const float* w1   = (const float*)d_in[9];
  const float* b1   = (const float*)d_in[10];
  const float* w2   = (const float*)d_in[11];
  const float* b2   = (const float*)d_in[12];
  const float* ln1g = (const float*)d_in[13];
  const float* ln1b = (const float*)d_in[14];
  const float* ln2g = (const float*)d_in[15];
  const float* ln2b = (const float*)d_in[16];
  float* out = (float*)d_out;

  char* ws = (char*)d_ws;
  size_t off = 0;
  auto alloc = [&](size_t bytes) { void* p = ws + off; off += (bytes + 255) & ~(size_t)255; return p; };
  ushort* h    = (ushort*)alloc((size_t)NTOK * DMODEL * 2);       // ln1 out; later ln2 out
  ushort* wqT  = (ushort*)alloc((size_t)DMODEL * DMODEL * 2);
  ushort* wkT  = (ushort*)alloc((size_t)DMODEL * DMODEL * 2);
  ushort* wvT  = (ushort*)alloc((size_t)DMODEL * DMODEL * 2);
  ushort* woT  = (ushort*)alloc((size_t)DMODEL * DMODEL * 2);
  ushort* qb   = (ushort*)alloc((size_t)NTOK * DMODEL * 2);
  ushort* kb   = (ushort*)alloc((size_t)NTOK * DMODEL * 2);
  ushort* vb   = (ushort*)alloc((size_t)NTOK * DMODEL * 2);
  ushort* vt   = (ushort*)alloc((size_t)64 * HDIM * S_LEN * 2);   // [bh][hd][s]
  ushort* sc   = (ushort*)alloc((size_t)32 * S_LEN * S_LEN * 2);  // 32 heads bf16 scores/P (64MB)
  // dead-region reuse:
  ushort* w1T  = sc + (size_t)16 * 1024 * 1024;   // 8MB  [FF][D], written after attention
  ushort* w2T  = w1T + (size_t)4 * 1024 * 1024;   // 8MB  [D][FF]
  ushort* gact = sc;                               // 32MB [4096][4096] bf16, after attention
  ushort* attn = qb;                               // PV writes batches already consumed by scores

  dim3 tb32(32, 8);
  // weight transposes (f32 -> bf16, [K][M] -> [M][K])
  hipLaunchKernelGGL((transpose_cvt<float>), dim3(DMODEL/32, DMODEL/32, 1), tb32, 0, stream,
                     wq, wqT, DMODEL, DMODEL, 0, 0, 0);
  hipLaunchKernelGGL((transpose_cvt<float>), dim3(DMODEL/32, DMODEL/32, 1), tb32, 0, stream,
                     wk, wkT, DMODEL, DMODEL, 0, 0, 0);
  hipLaunchKernelGGL((transpose_cvt<float>), dim3(DMODEL/32, DMODEL/32, 1), tb32, 0, stream,
                     wv, wvT, DMODEL, DMODEL, 0, 0, 0);
  hipLaunchKernelGGL((transpose_cvt<float>), dim3(DMODEL/32, DMODEL/32, 1), tb32, 0, stream,
                     wo, woT, DMODEL, DMODEL, 0, 0, 0);

  // LN1
  hipLaunchKernelGGL(ln_kernel, dim3(NTOK), dim3(256), 0, stream, x, ln1g, ln1b, h);

  // Q,K,V GEMMs: [4096,1024] = h @ W + b
  hipLaunchKernelGGL((gemm_bt<0, true, false, ushort>), dim3(8, 32, 1), dim3(256), 0, stream,
                     h, wqT, qb, bq, (const float*)nullptr,
                     DMODEL, DMODEL, DMODEL, DMODEL, DMODEL, 0L, 0L, 0L, 0L, 0L, 0L);
  hipLaunchKernelGGL((gemm_bt<0, true, false, ushort>), dim3(8, 32, 1), dim3(256), 0, stream,
                     h, wkT, kb, bk, (const float*)nullptr,
                     DMODEL, DMODEL, DMODEL, DMODEL, DMODEL, 0L, 0L, 0L, 0L, 0L, 0L);
  hipLaunchKernelGGL((gemm_bt<0, true, false, ushort>), dim3(8, 32, 1), dim3(256), 0, stream,
                     h, wvT, vb, bv, (const float*)nullptr,
                     DMODEL, DMODEL, DMODEL, DMODEL, DMODEL, 0L, 0L, 0L, 0L, 0L, 0L);

  // V transpose per (b,h): [s][hd] -> [hd][s], all 64 heads
  hipLaunchKernelGGL((transpose_cvt<ushort>), dim3(HDIM/32, S_LEN/32, 64), tb32, 0, stream,
                     vb, vt, DMODEL, S_LEN, (long)S_LEN * DMODEL, 64L, (long)HDIM * S_LEN);

  // attention: 2 groups of 32 heads (= 2 full batches each)
  for (int g = 0; g < 2; ++g) {
    const ushort* qg = qb + (long)g * 2 * S_LEN * DMODEL;
    const ushort* kg = kb + (long)g * 2 * S_LEN * DMODEL;
    // scores[z][sq][sk] = q·k (bf16 out, unscaled; softmax folds 1/8)
    hipLaunchKernelGGL((gemm_bt<0, false, false, ushort>), dim3(8, 8, 32), dim3(256), 0, stream,
                       qg, kg, sc, (const float*)nullptr, (const float*)nullptr,
                       S_LEN, HDIM, DMODEL, DMODEL, S_LEN,
                       (long)S_LEN * DMODEL, 64L,
                       (long)S_LEN * DMODEL, 64L,
                       16L * S_LEN * S_LEN, (long)S_LEN * S_LEN);
    hipLaunchKernelGGL(softmax_bf16, dim3(32 * S_LEN), dim3(256), 0, stream, sc);
    // attn[b, sq, h*64+hd] = P @ V^T
    hipLaunchKernelGGL((gemm_bt<0, false, false, ushort>), dim3(1, 8, 32), dim3(256), 0, stream,
                       sc, vt + (long)g * 32 * HDIM * S_LEN,
                       attn + (long)g * 2 * S_LEN * DMODEL,
                       (const float*)nullptr, (const float*)nullptr,
                       HDIM, S_LEN, S_LEN, S_LEN, DMODEL,
                       16L * S_LEN * S_LEN, (long)S_LEN * S_LEN,
                       16L * HDIM * S_LEN, (long)HDIM * S_LEN,
                       (long)S_LEN * DMODEL, 64L);
  }

  // x1 = x + attn @ wo + bo  -> d_out (f32)
  hipLaunchKernelGGL((gemm_bt<0, true, true, float>), dim3(8, 32, 1), dim3(256), 0, stream,
                     attn, woT, out, bo, x,
                     DMODEL, DMODEL, DMODEL, DMODEL, DMODEL, 0L, 0L, 0L, 0L, 0L, 0L);
  // LN2 on x1
  hipLaunchKernelGGL(ln_kernel, dim3(NTOK), dim3(256), 0, stream, out, ln2g, ln2b, h);
  // FFN weight transposes (into dead scores region)
  hipLaunchKernelGGL((transpose_cvt<float>), dim3(FFDIM/32, DMODEL/32, 1), tb32, 0, stream,
                     w1, w1T, FFDIM, DMODEL, 0, 0, 0);
  hipLaunchKernelGGL((transpose_cvt<float>), dim3(DMODEL/32, FFDIM/32, 1), tb32, 0, stream,
                     w2, w2T, DMODEL, FFDIM, 0, 0, 0);
  // FFN1: gelu(h @ w1 + b1) -> gact bf16 [4096][4096]
  hipLaunchKernelGGL((gemm_bt<1, true, false, ushort>), dim3(32, 32, 1), dim3(256), 0, stream,
                     h, w1T, gact, b1, (const float*)nullptr,
                     FFDIM, DMODEL, DMODEL, DMODEL, FFDIM, 0L, 0L, 0L, 0L, 0L, 0L);
  // FFN2: out = x1 + gact @ w2 + b2  (residual = current d_out)
  hipLaunchKernelGGL((gemm_bt<0, true, true, float>), dim3(8, 32, 1), dim3(256), 0, stream,
                     gact, w2T, out, b2, out,
                     DMODEL, FFDIM, FFDIM, FFDIM, DMODEL, 0L, 0L, 0L, 0L, 0L, 0L);
  (void)in_sizes; (void)n_in; (void)out_size; (void)ws_size;
}

// Round 3
// 461.380 us; speedup vs baseline: 1.3325x; 1.0400x over previous
//
#include <hip/hip_runtime.h>
#include <hip/hip_bf16.h>
#include <cstdint>

// ---- problem constants ----
#define S_LEN  1024
#define DMODEL 1024
#define NTOK   4096   // B*S = 4*1024
#define NHEAD  16
#define HDIM   64
#define FFDIM  4096
#define NBATCH 4

using bf16x8 = __attribute__((ext_vector_type(8))) short;
using f32x4  = __attribute__((ext_vector_type(4))) float;

__device__ __forceinline__ ushort f2bf(float f) {
  union { float f; uint32_t u; } a; a.f = f;
  uint32_t u = a.u;
  u += 0x7FFFu + ((u >> 16) & 1u);   // RNE
  return (ushort)(u >> 16);
}
__device__ __forceinline__ float bf2f(ushort u) {
  union { uint32_t u; float f; } c; c.u = ((uint32_t)u) << 16; return c.f;
}
__device__ __forceinline__ float ld_as_float(const float* p, long i) { return p[i]; }
__device__ __forceinline__ float ld_as_float(const ushort* p, long i) { return bf2f(p[i]); }
__device__ __forceinline__ void st_out(float* C, long i, float v) { C[i] = v; }
__device__ __forceinline__ void st_out(ushort* C, long i, float v) { C[i] = f2bf(v); }

// async global->LDS, 16B per lane; LDS dest = wave-uniform base + lane*16
__device__ __forceinline__ void gld_lds16(const void* g, void* l) {
  __builtin_amdgcn_global_load_lds((const __attribute__((address_space(1))) void*)g,
                                   (__attribute__((address_space(3))) void*)l, 16, 0, 0);
}

// ---------------- LayerNorm (row of 1024 f32) -> bf16 ----------------
__global__ __launch_bounds__(256) void ln_kernel(const float* __restrict__ x,
    const float* __restrict__ g, const float* __restrict__ b,
    ushort* __restrict__ out) {
  int row = blockIdx.x;
  int tid = threadIdx.x;
  const float4* xr = (const float4*)(x + (long)row * DMODEL);
  float4 v = xr[tid];
  float s  = v.x + v.y + v.z + v.w;
  float s2 = v.x*v.x + v.y*v.y + v.z*v.z + v.w*v.w;
  for (int off = 32; off; off >>= 1) { s += __shfl_down(s, off); s2 += __shfl_down(s2, off); }
  __shared__ float red[8];
  int wid = tid >> 6, lane = tid & 63;
  if (lane == 0) { red[wid] = s; red[wid + 4] = s2; }
  __syncthreads();
  if (tid == 0) {
    red[0] = red[0] + red[1] + red[2] + red[3];
    red[4] = red[4] + red[5] + red[6] + red[7];
  }
  __syncthreads();
  float mu  = red[0] * (1.0f / DMODEL);
  float var = red[4] * (1.0f / DMODEL) - mu * mu;
  float rs  = rsqrtf(var + 1e-5f);
  float4 gg = ((const float4*)g)[tid];
  float4 bb = ((const float4*)b)[tid];
  ushort4 o;
  o.x = f2bf((v.x - mu) * rs * gg.x + bb.x);
  o.y = f2bf((v.y - mu) * rs * gg.y + bb.y);
  o.z = f2bf((v.z - mu) * rs * gg.z + bb.z);
  o.w = f2bf((v.w - mu) * rs * gg.w + bb.w);
  ((ushort4*)(out + (long)row * DMODEL))[tid] = o;
}

// ---------------- row softmax, bf16 in-place (1024 elems), scale 1/8 folded ----------------
__global__ __launch_bounds__(256) void softmax_bf16(ushort* __restrict__ sc) {
  long row = blockIdx.x;
  int tid = threadIdx.x;
  ushort4* rp = (ushort4*)(sc + row * S_LEN);
  ushort4 u = rp[tid];
  float4 v;
  v.x = bf2f(u.x); v.y = bf2f(u.y); v.z = bf2f(u.z); v.w = bf2f(u.w);
  float mx = fmaxf(fmaxf(v.x, v.y), fmaxf(v.z, v.w));
  for (int off = 32; off; off >>= 1) mx = fmaxf(mx, __shfl_xor(mx, off));
  __shared__ float red[8];
  int wid = tid >> 6, lane = tid & 63;
  if (lane == 0) red[wid] = mx;
  __syncthreads();
  if (tid == 0) red[0] = fmaxf(fmaxf(red[0], red[1]), fmaxf(red[2], red[3]));
  __syncthreads();
  mx = red[0];
  float4 e;
  e.x = expf((v.x - mx) * 0.125f);
  e.y = expf((v.y - mx) * 0.125f);
  e.z = expf((v.z - mx) * 0.125f);
  e.w = expf((v.w - mx) * 0.125f);
  float s = e.x + e.y + e.z + e.w;
  for (int off = 32; off; off >>= 1) s += __shfl_xor(s, off);
  if (lane == 0) red[4 + wid] = s;
  __syncthreads();
  if (tid == 0) red[4] = red[4] + red[5] + red[6] + red[7];
  __syncthreads();
  float inv = 1.0f / red[4];
  ushort4 o;
  o.x = f2bf(e.x * inv); o.y = f2bf(e.y * inv);
  o.z = f2bf(e.z * inv); o.w = f2bf(e.w * inv);
  rp[tid] = o;
}

// ---------------- bias concat: [bq|bk|bv] -> 3072 floats ----------------
__global__ __launch_bounds__(256) void concat3(const float* __restrict__ a,
    const float* __restrict__ b, const float* __restrict__ c, float* __restrict__ o) {
  int i = blockIdx.x * 256 + threadIdx.x;
  o[i] = (i < 1024) ? a[i] : ((i < 2048) ? b[i - 1024] : c[i - 2048]);
}

// ---------------- transpose + convert to bf16 ----------------
// in: logical [R][C], row stride ldin (dtype TIN); out: [C][R] bf16, row stride ldout.
// per-z input offset = (z>>4)*inZhi + (z&15)*inZlo ; per-z output offset = z*outZ.
template <typename TIN>
__global__ __launch_bounds__(256) void transpose_cvt(const TIN* __restrict__ in,
    ushort* __restrict__ out, int ldin, int ldout,
    long inZhi, long inZlo, long outZ) {
  int z = blockIdx.z;
  in  += (long)(z >> 4) * inZhi + (long)(z & 15) * inZlo;
  out += (long)z * outZ;
  __shared__ float tile[32][33];
  int c0 = blockIdx.x * 32, r0 = blockIdx.y * 32;
  int tx = threadIdx.x, ty = threadIdx.y;
  for (int i = ty; i < 32; i += 8)
    tile[i][tx] = ld_as_float(in, (long)(r0 + i) * ldin + c0 + tx);
  __syncthreads();
  for (int i = ty; i < 32; i += 8)
    out[(long)(c0 + i) * ldout + r0 + tx] = f2bf(tile[tx][i]);
}

// ---------------- bf16 MFMA GEMM, 2-deep pipelined:  C[n,m] = A[n,:]·BT[m,:] ----------------
// 128x128 tile, BK=64, 4 waves (2x2), 16x16x32 bf16 MFMA, global_load_lds width-16,
// double-buffered linear [128][64] LDS, counted vmcnt (prefetch stays in flight across raw
// s_barrier). XCD-chunked block swizzle (requires gridDim.x*gridDim.y % 8 == 0).
// N%128==0, K%64==0; M guarded. per-z offsets: (z>>4)*Zhi + (z&15)*Zlo.
template <int ACT, bool BIAS, bool RES, typename TOUT>
__global__ __launch_bounds__(256) void gemm_bt(
    const ushort* __restrict__ A, const ushort* __restrict__ BT, TOUT* __restrict__ C,
    const float* __restrict__ bias, const float* __restrict__ resp,
    int M, int K, int lda, int ldb, int ldc,
    long aZhi, long aZlo, long bZhi, long bZlo, long cZhi, long cZlo) {
  __shared__ __align__(16) ushort lA[2][128 * 64];
  __shared__ __align__(16) ushort lB[2][128 * 64];
  int z = blockIdx.z;
  A  += (long)(z >> 4) * aZhi + (long)(z & 15) * aZlo;
  BT += (long)(z >> 4) * bZhi + (long)(z & 15) * bZlo;
  long coff = (long)(z >> 4) * cZhi + (long)(z & 15) * cZlo;
  // XCD-chunked bijective swizzle over the x-y plane
  int gx = gridDim.x;
  int nwg = gx * gridDim.y;
  int lin = blockIdx.x + gx * blockIdx.y;
  int wg = (lin & 7) * (nwg >> 3) + (lin >> 3);
  int n0 = (wg / gx) * 128, m0 = (wg % gx) * 128;
  int tid = threadIdx.x, lane = tid & 63, wid = tid >> 6;
  int wr = wid >> 1, wc = wid & 1;
  int lrow = lane >> 3, lk = (lane & 7) << 3;
  int Mm1 = M - 1;
  f32x4 acc[4][4];
#pragma unroll
  for (int i = 0; i < 4; i++)
#pragma unroll
    for (int j = 0; j < 4; j++) acc[i][j] = (f32x4){0.f, 0.f, 0.f, 0.f};

  auto STAGE = [&](int kt, int buf) {
    const ushort* Ak = A + (kt << 6) + lk;
    const ushort* Bk = BT + (kt << 6) + lk;
#pragma unroll
    for (int c = 0; c < 4; ++c) {
      int ch = (wid << 2) | c;          // chunk 0..15 (8 rows each)
      int rb = (ch << 3) + lrow;        // row 0..127
      gld_lds16(Ak + (long)(n0 + rb) * lda, &lA[buf][ch << 9]);
      int mrow = min(m0 + rb, Mm1);
      gld_lds16(Bk + (long)mrow * ldb, &lB[buf][ch << 9]);
    }
  };

  int nK = K >> 6;
  STAGE(0, 0);                          // prologue: 8 loads in flight
  for (int kt = 0; kt < nK; ++kt) {
    int cur = kt & 1;
    if (kt + 1 < nK) {
      STAGE(kt + 1, cur ^ 1);           // 8 more loads; 16 outstanding
      asm volatile("s_waitcnt vmcnt(8)" ::: "memory");   // cur buffer's 8 retired
    } else {
      asm volatile("s_waitcnt vmcnt(0)" ::: "memory");
    }
    __builtin_amdgcn_s_barrier();       // raw barrier: prefetch stays in flight
    __builtin_amdgcn_sched_barrier(0);
#pragma unroll
    for (int kk = 0; kk < 2; ++kk) {
      int kf = (kk << 5) + ((lane >> 4) << 3);
      bf16x8 af[4], bfr[4];
#pragma unroll
      for (int i = 0; i < 4; i++) {
        af[i]  = *(const bf16x8*)(&lA[cur][((wr << 6) + (i << 4) + (lane & 15)) * 64 + kf]);
        bfr[i] = *(const bf16x8*)(&lB[cur][((wc << 6) + (i << 4) + (lane & 15)) * 64 + kf]);
      }
#pragma unroll
      for (int i = 0; i < 4; i++)
#pragma unroll
        for (int j = 0; j < 4; j++)
          acc[i][j] = __builtin_amdgcn_mfma_f32_16x16x32_bf16(af[i], bfr[j], acc[i][j], 0, 0, 0);
    }
    asm volatile("s_waitcnt lgkmcnt(0)" ::: "memory");   // all LDS reads of cur retired
    __builtin_amdgcn_s_barrier();       // safe to overwrite cur next iteration
    __builtin_amdgcn_sched_barrier(0);
  }
  // epilogue: C/D layout col=lane&15, row=(lane>>4)*4+q  (m89/m91-verified)
#pragma unroll
  for (int i = 0; i < 4; i++) {
    int rbase = n0 + wr * 64 + i * 16 + ((lane >> 4) << 2);
#pragma unroll
    for (int j = 0; j < 4; j++) {
      int col = m0 + wc * 64 + j * 16 + (lane & 15);
      if (col < M) {
        float bv = BIAS ? bias[col] : 0.0f;
#pragma unroll
        for (int q = 0; q < 4; q++) {
          int rowg = rbase + q;
          float vv = acc[i][j][q] + bv;
          if (ACT == 1) vv = 0.5f * vv * (1.0f + erff(vv * 0.70710678118f));
          long idx = coff + (long)rowg * ldc + col;
          if (RES) vv += resp[idx];
          st_out(C, idx, vv);
        }
      }
    }
  }
}

// ---------------- host orchestration ----------------
extern "C" void kernel_launch(void* const* d_in, const int* in_sizes, int n_in,
                              void* d_out, int out_size, void* d_ws, size_t ws_size,
                              hipStream_t stream) {
  const float* x    = (const float*)d_in[0];
  const float* wq   = (const float*)d_in[1];
  const float* bq   = (const float*)d_in[2];
  const float* wk   = (const float*)d_in[3];
  const float* bk   = (const float*)d_in[4];
  const float* wv   = (const float*)d_in[5];
  const float* bv   = (const float*)d_in[6];
  const float* wo   = (const float*)d_in[7];
  const float* bo   = (const float*)d_in[8];
  const float* w1   = (const float*)d_in[9];
  const float* b1   = (const float*)d_in[10];
  const float* w2   = (const float*)d_in[11];
  const float* b2   = (const float*)d_in[12];
  const float* ln1g = (const float*)d_in[13];
  const float* ln1b = (const float*)d_in[14];
  const float* ln2g = (const float*)d_in[15];
  const float* ln2b = (const float*)d_in[16];
  float* out = (float*)d_out;

  char* ws = (char*)d_ws;
  size_t off = 0;
  auto alloc = [&](size_t bytes) { void* p = ws + off; off += (bytes + 255) & ~(size_t)255; return p; };
  ushort* h     = (ushort*)alloc((size_t)NTOK * DMODEL * 2);        // 8MB  ln1/ln2 out
  ushort* wqkvT = (ushort*)alloc((size_t)3 * DMODEL * DMODEL * 2);  // 6MB  [3072][1024]
  ushort* woT   = (ushort*)alloc((size_t)DMODEL * DMODEL * 2);      // 2MB
  float*  bqkv  = (float*)alloc((size_t)3 * DMODEL * 4);            // 12KB
  ushort* qkv   = (ushort*)alloc((size_t)NTOK * 3 * DMODEL * 2);    // 24MB [4096][3072]
  ushort* vt    = (ushort*)alloc((size_t)64 * HDIM * S_LEN * 2);    // 8MB  [bh][hd][s]
  ushort* attn  = (ushort*)alloc((size_t)NTOK * DMODEL * 2);        // 8MB
  ushort* sc    = (ushort*)alloc((size_t)32 * S_LEN * S_LEN * 2);   // 64MB 32-head scores/P
  // dead-region reuse (after attention):
  ushort* w1T  = sc + (size_t)16 * 1024 * 1024;   // 8MB  [FF][D]
  ushort* w2T  = w1T + (size_t)4 * 1024 * 1024;   // 8MB  [D][FF]
  ushort* gact = sc;                               // 32MB [4096][4096] bf16

  dim3 tb32(32, 8);
  // weight transposes (f32 -> bf16, [K][M] -> [M][K]); wq/wk/wv stacked into wqkvT
  hipLaunchKernelGGL((transpose_cvt<float>), dim3(DMODEL/32, DMODEL/32, 1), tb32, 0, stream,
                     wq, wqkvT, DMODEL, DMODEL, 0, 0, 0);
  hipLaunchKernelGGL((transpose_cvt<float>), dim3(DMODEL/32, DMODEL/32, 1), tb32, 0, stream,
                     wk, wqkvT + (size_t)DMODEL * DMODEL, DMODEL, DMODEL, 0, 0, 0);
  hipLaunchKernelGGL((transpose_cvt<float>), dim3(DMODEL/32, DMODEL/32, 1), tb32, 0, stream,
                     wv, wqkvT + (size_t)2 * DMODEL * DMODEL, DMODEL, DMODEL, 0, 0, 0);
  hipLaunchKernelGGL((transpose_cvt<float>), dim3(DMODEL/32, DMODEL/32, 1), tb32, 0, stream,
                     wo, woT, DMODEL, DMODEL, 0, 0, 0);
  hipLaunchKernelGGL(concat3, dim3(12), dim3(256), 0, stream, bq, bk, bv, bqkv);

  // LN1
  hipLaunchKernelGGL(ln_kernel, dim3(NTOK), dim3(256), 0, stream, x, ln1g, ln1b, h);

  // merged QKV GEMM: [4096,3072] = h @ [wq|wk|wv] + bqkv
  hipLaunchKernelGGL((gemm_bt<0, true, false, ushort>), dim3(24, 32, 1), dim3(256), 0, stream,
                     h, wqkvT, qkv, bqkv, (const float*)nullptr,
                     3 * DMODEL, DMODEL, DMODEL, DMODEL, 3 * DMODEL, 0L, 0L, 0L, 0L, 0L, 0L);

  // V transpose per (b,h): qkv[:, 2048 + h*64 ..] -> vt [bh][hd][s]
  hipLaunchKernelGGL((transpose_cvt<ushort>), dim3(HDIM/32, S_LEN/32, 64), tb32, 0, stream,
                     qkv + 2 * DMODEL, vt, 3 * DMODEL, S_LEN,
                     (long)S_LEN * 3 * DMODEL, 64L, (long)HDIM * S_LEN);

  // attention: 2 groups of 32 heads (= 2 full batches each)
  for (int g = 0; g < 2; ++g) {
    const ushort* qg = qkv + (long)g * 2 * S_LEN * 3 * DMODEL;
    // scores[z][sq][sk] = q·k (bf16 out, unscaled; softmax folds 1/8)
    hipLaunchKernelGGL((gemm_bt<0, false, false, ushort>), dim3(8, 8, 32), dim3(256), 0, stream,
                       qg, qg + DMODEL, sc, (const float*)nullptr, (const float*)nullptr,
                       S_LEN, HDIM, 3 * DMODEL, 3 * DMODEL, S_LEN,
                       (long)S_LEN * 3 * DMODEL, 64L,
                       (long)S_LEN * 3 * DMODEL, 64L,
                       16L * S_LEN * S_LEN, (long)S_LEN * S_LEN);
    hipLaunchKernelGGL(softmax_bf16, dim3(32 * S_LEN), dim3(256), 0, stream, sc);
    // attn[b, sq, h*64+hd] = P @ V^T
    hipLaunchKernelGGL((gemm_bt<0, false, false, ushort>), dim3(1, 8, 32), dim3(256), 0, stream,
                       sc, vt + (long)g * 32 * HDIM * S_LEN,
                       attn + (long)g * 2 * S_LEN * DMODEL,
                       (const float*)nullptr, (const float*)nullptr,
                       HDIM, S_LEN, S_LEN, S_LEN, DMODEL,
                       16L * S_LEN * S_LEN, (long)S_LEN * S_LEN,
                       16L * HDIM * S_LEN, (long)HDIM * S_LEN,
                       (long)S_LEN * DMODEL, 64L);
  }

  // x1 = x + attn @ wo + bo  -> d_out (f32)
  hipLaunchKernelGGL((gemm_bt<0, true, true, float>), dim3(8, 32, 1), dim3(256), 0, stream,
                     attn, woT, out, bo, x,
                     DMODEL, DMODEL, DMODEL, DMODEL, DMODEL, 0L, 0L, 0L, 0L, 0L, 0L);
  // LN2 on x1
  hipLaunchKernelGGL(ln_kernel, dim3(NTOK), dim3(256), 0, stream, out, ln2g, ln2b, h);
  // FFN weight transposes (into dead scores region)
  hipLaunchKernelGGL((transpose_cvt<float>), dim3(FFDIM/32, DMODEL/32, 1), tb32, 0, stream,
                     w1, w1T, FFDIM, DMODEL, 0, 0, 0);
  hipLaunchKernelGGL((transpose_cvt<float>), dim3(DMODEL/32, FFDIM/32, 1), tb32, 0, stream,
                     w2, w2T, DMODEL, FFDIM, 0, 0, 0);
  // FFN1: gelu(h @ w1 + b1) -> gact bf16 [4096][4096]
  hipLaunchKernelGGL((gemm_bt<1, true, false, ushort>), dim3(32, 32, 1), dim3(256), 0, stream,
                     h, w1T, gact, b1, (const float*)nullptr,
                     FFDIM, DMODEL, DMODEL, DMODEL, FFDIM, 0L, 0L, 0L, 0L, 0L, 0L);
  // FFN2: out = x1 + gact @ w2 + b2  (residual = current d_out)
  hipLaunchKernelGGL((gemm_bt<0, true, true, float>), dim3(8, 32, 1), dim3(256), 0, stream,
                     gact, w2T, out, b2, out,
                     DMODEL, FFDIM, FFDIM, FFDIM, DMODEL, 0L, 0L, 0L, 0L, 0L, 0L);
  (void)in_sizes; (void)n_in; (void)out_size; (void)ws_size;
}

// Round 4
// 409.526 us; speedup vs baseline: 1.5012x; 1.1266x over previous
//
#include <hip/hip_runtime.h>
#include <hip/hip_bf16.h>
#include <cstdint>

// ---- problem constants ----
#define S_LEN  1024
#define DMODEL 1024
#define NTOK   4096   // B*S = 4*1024
#define NHEAD  16
#define HDIM   64
#define FFDIM  4096
#define NBATCH 4

using bf16x8 = __attribute__((ext_vector_type(8))) short;
using f32x4  = __attribute__((ext_vector_type(4))) float;

__device__ __forceinline__ ushort f2bf(float f) {
  union { float f; uint32_t u; } a; a.f = f;
  uint32_t u = a.u;
  u += 0x7FFFu + ((u >> 16) & 1u);   // RNE
  return (ushort)(u >> 16);
}
__device__ __forceinline__ float bf2f(ushort u) {
  union { uint32_t u; float f; } c; c.u = ((uint32_t)u) << 16; return c.f;
}
__device__ __forceinline__ float ld_as_float(const float* p, long i) { return p[i]; }
__device__ __forceinline__ float ld_as_float(const ushort* p, long i) { return bf2f(p[i]); }
__device__ __forceinline__ void st_out(float* C, long i, float v) { C[i] = v; }
__device__ __forceinline__ void st_out(ushort* C, long i, float v) { C[i] = f2bf(v); }

// async global->LDS, 16B per lane; LDS dest = wave-uniform base + lane*16 (linear!)
__device__ __forceinline__ void gld_lds16(const void* g, void* l) {
  __builtin_amdgcn_global_load_lds((const __attribute__((address_space(1))) void*)g,
                                   (__attribute__((address_space(3))) void*)l, 16, 0, 0);
}
// hardware f32 atomic add (no return) — avoids CAS-loop fallback of atomicAdd(float)
__device__ __forceinline__ void atomic_add_f32(float* p, float v) {
  asm volatile("global_atomic_add_f32 %0, %1, off" :: "v"(p), "v"(v) : "memory");
}

// ---------------- LayerNorm (row of 1024 f32) -> bf16 ----------------
__global__ __launch_bounds__(256) void ln_kernel(const float* __restrict__ x,
    const float* __restrict__ g, const float* __restrict__ b,
    ushort* __restrict__ out) {
  int row = blockIdx.x;
  int tid = threadIdx.x;
  const float4* xr = (const float4*)(x + (long)row * DMODEL);
  float4 v = xr[tid];
  float s  = v.x + v.y + v.z + v.w;
  float s2 = v.x*v.x + v.y*v.y + v.z*v.z + v.w*v.w;
  for (int off = 32; off; off >>= 1) { s += __shfl_down(s, off); s2 += __shfl_down(s2, off); }
  __shared__ float red[8];
  int wid = tid >> 6, lane = tid & 63;
  if (lane == 0) { red[wid] = s; red[wid + 4] = s2; }
  __syncthreads();
  if (tid == 0) {
    red[0] = red[0] + red[1] + red[2] + red[3];
    red[4] = red[4] + red[5] + red[6] + red[7];
  }
  __syncthreads();
  float mu  = red[0] * (1.0f / DMODEL);
  float var = red[4] * (1.0f / DMODEL) - mu * mu;
  float rs  = rsqrtf(var + 1e-5f);
  float4 gg = ((const float4*)g)[tid];
  float4 bb = ((const float4*)b)[tid];
  ushort4 o;
  o.x = f2bf((v.x - mu) * rs * gg.x + bb.x);
  o.y = f2bf((v.y - mu) * rs * gg.y + bb.y);
  o.z = f2bf((v.z - mu) * rs * gg.z + bb.z);
  o.w = f2bf((v.w - mu) * rs * gg.w + bb.w);
  ((ushort4*)(out + (long)row * DMODEL))[tid] = o;
}

// ---------------- row softmax, bf16 in-place (1024 elems), scale 1/8 folded ----------------
__global__ __launch_bounds__(256) void softmax_bf16(ushort* __restrict__ sc) {
  long row = blockIdx.x;
  int tid = threadIdx.x;
  ushort4* rp = (ushort4*)(sc + row * S_LEN);
  ushort4 u = rp[tid];
  float4 v;
  v.x = bf2f(u.x); v.y = bf2f(u.y); v.z = bf2f(u.z); v.w = bf2f(u.w);
  float mx = fmaxf(fmaxf(v.x, v.y), fmaxf(v.z, v.w));
  for (int off = 32; off; off >>= 1) mx = fmaxf(mx, __shfl_xor(mx, off));
  __shared__ float red[8];
  int wid = tid >> 6, lane = tid & 63;
  if (lane == 0) red[wid] = mx;
  __syncthreads();
  if (tid == 0) red[0] = fmaxf(fmaxf(red[0], red[1]), fmaxf(red[2], red[3]));
  __syncthreads();
  mx = red[0];
  float4 e;
  e.x = expf((v.x - mx) * 0.125f);
  e.y = expf((v.y - mx) * 0.125f);
  e.z = expf((v.z - mx) * 0.125f);
  e.w = expf((v.w - mx) * 0.125f);
  float s = e.x + e.y + e.z + e.w;
  for (int off = 32; off; off >>= 1) s += __shfl_xor(s, off);
  if (lane == 0) red[4 + wid] = s;
  __syncthreads();
  if (tid == 0) red[4] = red[4] + red[5] + red[6] + red[7];
  __syncthreads();
  float inv = 1.0f / red[4];
  ushort4 o;
  o.x = f2bf(e.x * inv); o.y = f2bf(e.y * inv);
  o.z = f2bf(e.z * inv); o.w = f2bf(e.w * inv);
  rp[tid] = o;
}

// ---------------- bias concat: [bq|bk|bv] -> 3072 floats ----------------
__global__ __launch_bounds__(256) void concat3(const float* __restrict__ a,
    const float* __restrict__ b, const float* __restrict__ c, float* __restrict__ o) {
  int i = blockIdx.x * 256 + threadIdx.x;
  o[i] = (i < 1024) ? a[i] : ((i < 2048) ? b[i - 1024] : c[i - 2048]);
}

// ---------------- residual init: out[r][c] = x[r][c] + bias[c] ----------------
__global__ __launch_bounds__(256) void init_resid(const float* __restrict__ x,
    const float* __restrict__ bias, float* __restrict__ out) {
  int i = blockIdx.x * 256 + threadIdx.x;       // float4 index
  float4 v = ((const float4*)x)[i];
  float4 b = ((const float4*)bias)[i & 255];    // 1024/4 float4 per row
  v.x += b.x; v.y += b.y; v.z += b.z; v.w += b.w;
  ((float4*)out)[i] = v;
}

// ---------------- transpose + convert to bf16 ----------------
template <typename TIN>
__global__ __launch_bounds__(256) void transpose_cvt(const TIN* __restrict__ in,
    ushort* __restrict__ out, int ldin, int ldout,
    long inZhi, long inZlo, long outZ) {
  int z = blockIdx.z;
  in  += (long)(z >> 4) * inZhi + (long)(z & 15) * inZlo;
  out += (long)z * outZ;
  __shared__ float tile[32][33];
  int c0 = blockIdx.x * 32, r0 = blockIdx.y * 32;
  int tx = threadIdx.x, ty = threadIdx.y;
  for (int i = ty; i < 32; i += 8)
    tile[i][tx] = ld_as_float(in, (long)(r0 + i) * ldin + c0 + tx);
  __syncthreads();
  for (int i = ty; i < 32; i += 8)
    out[(long)(c0 + i) * ldout + r0 + tx] = f2bf(tile[tx][i]);
}

// ---------------- bf16 MFMA GEMM, 2-deep pipelined, T2-swizzled LDS ----------------
// C[n,m] = A[n,:]·BT[m,:]. 128x128 tile, BK=64, 4 waves, 16x16x32 MFMA.
// LDS layout: [128][64] with k-group XOR swizzle g' = g ^ (row&7), realized by
// pre-swizzling the per-lane GLOBAL source (LDS dest of global_load_lds is linear)
// and applying the same XOR on ds_read (rule #21: both-sides-or-neither).
// ATOMIC mode: blockIdx.z = K-chunk (offset z*aZlo/z*bZlo along k), epilogue does
// global_atomic_add_f32 into C; bias added by chunk z==0 only.
template <int ACT, bool BIAS, bool RES, typename TOUT, bool ATOMIC = false>
__global__ __launch_bounds__(256) void gemm_bt(
    const ushort* __restrict__ A, const ushort* __restrict__ BT, TOUT* __restrict__ C,
    const float* __restrict__ bias, const float* __restrict__ resp,
    int M, int K, int lda, int ldb, int ldc,
    long aZhi, long aZlo, long bZhi, long bZlo, long cZhi, long cZlo) {
  __shared__ __align__(16) ushort lA[2][128 * 64];
  __shared__ __align__(16) ushort lB[2][128 * 64];
  int z = blockIdx.z;
  A  += (long)(z >> 4) * aZhi + (long)(z & 15) * aZlo;
  BT += (long)(z >> 4) * bZhi + (long)(z & 15) * bZlo;
  long coff = (long)(z >> 4) * cZhi + (long)(z & 15) * cZlo;
  // XCD-chunked bijective swizzle over the x-y plane (requires nwg % 8 == 0)
  int gx = gridDim.x;
  int nwg = gx * gridDim.y;
  int lin = blockIdx.x + gx * blockIdx.y;
  int wg = (lin & 7) * (nwg >> 3) + (lin >> 3);
  int n0 = (wg / gx) * 128, m0 = (wg % gx) * 128;
  int tid = threadIdx.x, lane = tid & 63, wid = tid >> 6;
  int wr = wid >> 1, wc = wid & 1;
  int lrow = lane >> 3;                       // 0..7 (row within 8-row chunk)
  int swz = ((lane & 7) ^ lrow) << 3;         // pre-swizzled global k-offset (elements)
  int Mm1 = M - 1;
  f32x4 acc[4][4];
#pragma unroll
  for (int i = 0; i < 4; i++)
#pragma unroll
    for (int j = 0; j < 4; j++) acc[i][j] = (f32x4){0.f, 0.f, 0.f, 0.f};

  auto STAGE = [&](int kt, int buf) {
    const ushort* Ak = A + (kt << 6) + swz;
    const ushort* Bk = BT + (kt << 6) + swz;
#pragma unroll
    for (int c = 0; c < 4; ++c) {
      int ch = (wid << 2) | c;          // chunk 0..15 (8 rows each)
      int rb = (ch << 3) + lrow;        // row 0..127
      gld_lds16(Ak + (long)(n0 + rb) * lda, &lA[buf][ch << 9]);
      int mrow = min(m0 + rb, Mm1);
      gld_lds16(Bk + (long)mrow * ldb, &lB[buf][ch << 9]);
    }
  };

  int nK = K >> 6;
  STAGE(0, 0);                          // prologue: 8 loads in flight
  for (int kt = 0; kt < nK; ++kt) {
    int cur = kt & 1;
    if (kt + 1 < nK) {
      STAGE(kt + 1, cur ^ 1);           // 8 more loads; 16 outstanding
      asm volatile("s_waitcnt vmcnt(8)" ::: "memory");   // cur buffer's 8 retired
    } else {
      asm volatile("s_waitcnt vmcnt(0)" ::: "memory");
    }
    __builtin_amdgcn_s_barrier();       // raw barrier: prefetch stays in flight
    __builtin_amdgcn_sched_barrier(0);
#pragma unroll
    for (int kk = 0; kk < 2; ++kk) {
      int g = (kk << 2) | (lane >> 4);            // logical k-group 0..7
      int kfs = ((g ^ (lane & 7)) << 3);          // swizzled (row&7 == lane&7 for frag rows)
      bf16x8 af[4], bfr[4];
#pragma unroll
      for (int i = 0; i < 4; i++) {
        af[i]  = *(const bf16x8*)(&lA[cur][((wr << 6) + (i << 4) + (lane & 15)) * 64 + kfs]);
        bfr[i] = *(const bf16x8*)(&lB[cur][((wc << 6) + (i << 4) + (lane & 15)) * 64 + kfs]);
      }
#pragma unroll
      for (int i = 0; i < 4; i++)
#pragma unroll
        for (int j = 0; j < 4; j++)
          acc[i][j] = __builtin_amdgcn_mfma_f32_16x16x32_bf16(af[i], bfr[j], acc[i][j], 0, 0, 0);
    }
    asm volatile("s_waitcnt lgkmcnt(0)" ::: "memory");   // all LDS reads of cur retired
    __builtin_amdgcn_s_barrier();       // safe to overwrite cur next iteration
    __builtin_amdgcn_sched_barrier(0);
  }
  // epilogue: C/D layout col=lane&15, row=(lane>>4)*4+q  (m89/m91-verified)
#pragma unroll
  for (int i = 0; i < 4; i++) {
    int rbase = n0 + wr * 64 + i * 16 + ((lane >> 4) << 2);
#pragma unroll
    for (int j = 0; j < 4; j++) {
      int col = m0 + wc * 64 + j * 16 + (lane & 15);
      if (col < M) {
        float bv = (BIAS && (!ATOMIC || z == 0)) ? bias[col] : 0.0f;
#pragma unroll
        for (int q = 0; q < 4; q++) {
          int rowg = rbase + q;
          float vv = acc[i][j][q] + bv;
          if (ACT == 1) vv = 0.5f * vv * (1.0f + erff(vv * 0.70710678118f));
          long idx = coff + (long)rowg * ldc + col;
          if constexpr (ATOMIC) {
            atomic_add_f32((float*)&C[idx], vv);
          } else {
            if (RES) vv += resp[idx];
            st_out(C, idx, vv);
          }
        }
      }
    }
  }
}

// ---------------- host orchestration ----------------
extern "C" void kernel_launch(void* const* d_in, const int* in_sizes, int n_in,
                              void* d_out, int out_size, void* d_ws, size_t ws_size,
                              hipStream_t stream) {
  const float* x    = (const float*)d_in[0];
  const float* wq   = (const float*)d_in[1];
  const float* bq   = (const float*)d_in[2];
  const float* wk   = (const float*)d_in[3];
  const float* bk   = (const float*)d_in[4];
  const float* wv   = (const float*)d_in[5];
  const float* bv   = (const float*)d_in[6];
  const float* wo   = (const float*)d_in[7];
  const float* bo   = (const float*)d_in[8];
  const float* w1   = (const float*)d_in[9];
  const float* b1   = (const float*)d_in[10];
  const float* w2   = (const float*)d_in[11];
  const float* b2   = (const float*)d_in[12];
  const float* ln1g = (const float*)d_in[13];
  const float* ln1b = (const float*)d_in[14];
  const float* ln2g = (const float*)d_in[15];
  const float* ln2b = (const float*)d_in[16];
  float* out = (float*)d_out;

  char* ws = (char*)d_ws;
  size_t off = 0;
  auto alloc = [&](size_t bytes) { void* p = ws + off; off += (bytes + 255) & ~(size_t)255; return p; };
  ushort* h     = (ushort*)alloc((size_t)NTOK * DMODEL * 2);        // 8MB  ln1/ln2 out
  ushort* wqkvT = (ushort*)alloc((size_t)3 * DMODEL * DMODEL * 2);  // 6MB  [3072][1024]
  ushort* woT   = (ushort*)alloc((size_t)DMODEL * DMODEL * 2);      // 2MB
  float*  bqkv  = (float*)alloc((size_t)3 * DMODEL * 4);            // 12KB
  ushort* qkv   = (ushort*)alloc((size_t)NTOK * 3 * DMODEL * 2);    // 24MB [4096][3072]
  ushort* vt    = (ushort*)alloc((size_t)64 * HDIM * S_LEN * 2);    // 8MB  [bh][hd][s]
  ushort* attn  = (ushort*)alloc((size_t)NTOK * DMODEL * 2);        // 8MB
  ushort* sc    = (ushort*)alloc((size_t)32 * S_LEN * S_LEN * 2);   // 64MB 32-head scores/P
  // dead-region reuse (after attention):
  ushort* w1T  = sc + (size_t)16 * 1024 * 1024;   // 8MB  [FF][D]
  ushort* w2T  = w1T + (size_t)4 * 1024 * 1024;   // 8MB  [D][FF]
  ushort* gact = sc;                               // 32MB [4096][4096] bf16

  dim3 tb32(32, 8);
  // weight transposes (f32 -> bf16, [K][M] -> [M][K]); wq/wk/wv stacked into wqkvT
  hipLaunchKernelGGL((transpose_cvt<float>), dim3(DMODEL/32, DMODEL/32, 1), tb32, 0, stream,
                     wq, wqkvT, DMODEL, DMODEL, 0, 0, 0);
  hipLaunchKernelGGL((transpose_cvt<float>), dim3(DMODEL/32, DMODEL/32, 1), tb32, 0, stream,
                     wk, wqkvT + (size_t)DMODEL * DMODEL, DMODEL, DMODEL, 0, 0, 0);
  hipLaunchKernelGGL((transpose_cvt<float>), dim3(DMODEL/32, DMODEL/32, 1), tb32, 0, stream,
                     wv, wqkvT + (size_t)2 * DMODEL * DMODEL, DMODEL, DMODEL, 0, 0, 0);
  hipLaunchKernelGGL((transpose_cvt<float>), dim3(DMODEL/32, DMODEL/32, 1), tb32, 0, stream,
                     wo, woT, DMODEL, DMODEL, 0, 0, 0);
  hipLaunchKernelGGL(concat3, dim3(12), dim3(256), 0, stream, bq, bk, bv, bqkv);

  // LN1
  hipLaunchKernelGGL(ln_kernel, dim3(NTOK), dim3(256), 0, stream, x, ln1g, ln1b, h);

  // merged QKV GEMM: [4096,3072] = h @ [wq|wk|wv] + bqkv
  hipLaunchKernelGGL((gemm_bt<0, true, false, ushort>), dim3(24, 32, 1), dim3(256), 0, stream,
                     h, wqkvT, qkv, bqkv, (const float*)nullptr,
                     3 * DMODEL, DMODEL, DMODEL, DMODEL, 3 * DMODEL, 0L, 0L, 0L, 0L, 0L, 0L);

  // V transpose per (b,h): qkv[:, 2048 + h*64 ..] -> vt [bh][hd][s]
  hipLaunchKernelGGL((transpose_cvt<ushort>), dim3(HDIM/32, S_LEN/32, 64), tb32, 0, stream,
                     qkv + 2 * DMODEL, vt, 3 * DMODEL, S_LEN,
                     (long)S_LEN * 3 * DMODEL, 64L, (long)HDIM * S_LEN);

  // attention: 2 groups of 32 heads (= 2 full batches each)
  for (int g = 0; g < 2; ++g) {
    const ushort* qg = qkv + (long)g * 2 * S_LEN * 3 * DMODEL;
    // scores[z][sq][sk] = q·k (bf16 out, unscaled; softmax folds 1/8)
    hipLaunchKernelGGL((gemm_bt<0, false, false, ushort>), dim3(8, 8, 32), dim3(256), 0, stream,
                       qg, qg + DMODEL, sc, (const float*)nullptr, (const float*)nullptr,
                       S_LEN, HDIM, 3 * DMODEL, 3 * DMODEL, S_LEN,
                       (long)S_LEN * 3 * DMODEL, 64L,
                       (long)S_LEN * 3 * DMODEL, 64L,
                       16L * S_LEN * S_LEN, (long)S_LEN * S_LEN);
    hipLaunchKernelGGL(softmax_bf16, dim3(32 * S_LEN), dim3(256), 0, stream, sc);
    // attn[b, sq, h*64+hd] = P @ V^T
    hipLaunchKernelGGL((gemm_bt<0, false, false, ushort>), dim3(1, 8, 32), dim3(256), 0, stream,
                       sc, vt + (long)g * 32 * HDIM * S_LEN,
                       attn + (long)g * 2 * S_LEN * DMODEL,
                       (const float*)nullptr, (const float*)nullptr,
                       HDIM, S_LEN, S_LEN, S_LEN, DMODEL,
                       16L * S_LEN * S_LEN, (long)S_LEN * S_LEN,
                       16L * HDIM * S_LEN, (long)HDIM * S_LEN,
                       (long)S_LEN * DMODEL, 64L);
  }

  // out = x + bo (residual + bias init), then x1 += attn @ wo  (split-K=2, atomic)
  hipLaunchKernelGGL(init_resid, dim3(4096), dim3(256), 0, stream, x, bo, out);
  hipLaunchKernelGGL((gemm_bt<0, false, false, float, true>), dim3(8, 32, 2), dim3(256), 0, stream,
                     attn, woT, out, (const float*)nullptr, (const float*)nullptr,
                     DMODEL, 512, DMODEL, DMODEL, DMODEL,
                     0L, 512L, 0L, 512L, 0L, 0L);
  // LN2 on x1
  hipLaunchKernelGGL(ln_kernel, dim3(NTOK), dim3(256), 0, stream, out, ln2g, ln2b, h);
  // FFN weight transposes (into dead scores region)
  hipLaunchKernelGGL((transpose_cvt<float>), dim3(FFDIM/32, DMODEL/32, 1), tb32, 0, stream,
                     w1, w1T, FFDIM, DMODEL, 0, 0, 0);
  hipLaunchKernelGGL((transpose_cvt<float>), dim3(DMODEL/32, FFDIM/32, 1), tb32, 0, stream,
                     w2, w2T, DMODEL, FFDIM, 0, 0, 0);
  // FFN1: gelu(h @ w1 + b1) -> gact bf16 [4096][4096]
  hipLaunchKernelGGL((gemm_bt<1, true, false, ushort>), dim3(32, 32, 1), dim3(256), 0, stream,
                     h, w1T, gact, b1, (const float*)nullptr,
                     FFDIM, DMODEL, DMODEL, DMODEL, FFDIM, 0L, 0L, 0L, 0L, 0L, 0L);
  // FFN2: out += gact @ w2 + b2  (split-K=2, atomic; b2 on chunk 0; residual already in out)
  hipLaunchKernelGGL((gemm_bt<0, true, false, float, true>), dim3(8, 32, 2), dim3(256), 0, stream,
                     gact, w2T, out, b2, (const float*)nullptr,
                     DMODEL, 2048, FFDIM, FFDIM, DMODEL,
                     0L, 2048L, 0L, 2048L, 0L, 0L);
  (void)in_sizes; (void)n_in; (void)out_size; (void)ws_size;
}

// Round 5
// 338.278 us; speedup vs baseline: 1.8174x; 1.2106x over previous
//
#include <hip/hip_runtime.h>
#include <hip/hip_bf16.h>
#include <cstdint>

// ---- problem constants ----
#define S_LEN  1024
#define DMODEL 1024
#define NTOK   4096   // B*S = 4*1024
#define NHEAD  16
#define HDIM   64
#define FFDIM  4096
#define NBATCH 4

using bf16x8 = __attribute__((ext_vector_type(8))) short;
using f32x4  = __attribute__((ext_vector_type(4))) float;

__device__ __forceinline__ ushort f2bf(float f) {
  union { float f; uint32_t u; } a; a.f = f;
  uint32_t u = a.u;
  u += 0x7FFFu + ((u >> 16) & 1u);   // RNE
  return (ushort)(u >> 16);
}
__device__ __forceinline__ float bf2f(ushort u) {
  union { uint32_t u; float f; } c; c.u = ((uint32_t)u) << 16; return c.f;
}
__device__ __forceinline__ float ld_as_float(const float* p, long i) { return p[i]; }
__device__ __forceinline__ float ld_as_float(const ushort* p, long i) { return bf2f(p[i]); }
__device__ __forceinline__ void st_out(float* C, long i, float v) { C[i] = v; }
__device__ __forceinline__ void st_out(ushort* C, long i, float v) { C[i] = f2bf(v); }

// async global->LDS, 16B per lane; LDS dest = wave-uniform base + lane*16 (linear!)
__device__ __forceinline__ void gld_lds16(const void* g, void* l) {
  __builtin_amdgcn_global_load_lds((const __attribute__((address_space(1))) void*)g,
                                   (__attribute__((address_space(3))) void*)l, 16, 0, 0);
}
// hardware f32 atomic add (no return)
__device__ __forceinline__ void atomic_add_f32(float* p, float v) {
  asm volatile("global_atomic_add_f32 %0, %1, off" :: "v"(p), "v"(v) : "memory");
}

// ---------------- LayerNorm (row of 1024 f32) -> bf16 ----------------
__global__ __launch_bounds__(256) void ln_kernel(const float* __restrict__ x,
    const float* __restrict__ g, const float* __restrict__ b,
    ushort* __restrict__ out) {
  int row = blockIdx.x;
  int tid = threadIdx.x;
  const float4* xr = (const float4*)(x + (long)row * DMODEL);
  float4 v = xr[tid];
  float s  = v.x + v.y + v.z + v.w;
  float s2 = v.x*v.x + v.y*v.y + v.z*v.z + v.w*v.w;
  for (int off = 32; off; off >>= 1) { s += __shfl_down(s, off); s2 += __shfl_down(s2, off); }
  __shared__ float red[8];
  int wid = tid >> 6, lane = tid & 63;
  if (lane == 0) { red[wid] = s; red[wid + 4] = s2; }
  __syncthreads();
  if (tid == 0) {
    red[0] = red[0] + red[1] + red[2] + red[3];
    red[4] = red[4] + red[5] + red[6] + red[7];
  }
  __syncthreads();
  float mu  = red[0] * (1.0f / DMODEL);
  float var = red[4] * (1.0f / DMODEL) - mu * mu;
  float rs  = rsqrtf(var + 1e-5f);
  float4 gg = ((const float4*)g)[tid];
  float4 bb = ((const float4*)b)[tid];
  ushort4 o;
  o.x = f2bf((v.x - mu) * rs * gg.x + bb.x);
  o.y = f2bf((v.y - mu) * rs * gg.y + bb.y);
  o.z = f2bf((v.z - mu) * rs * gg.z + bb.z);
  o.w = f2bf((v.w - mu) * rs * gg.w + bb.w);
  ((ushort4*)(out + (long)row * DMODEL))[tid] = o;
}

// ---------------- bias concat: [bq|bk|bv] -> 3072 floats ----------------
__global__ __launch_bounds__(256) void concat3(const float* __restrict__ a,
    const float* __restrict__ b, const float* __restrict__ c, float* __restrict__ o) {
  int i = blockIdx.x * 256 + threadIdx.x;
  o[i] = (i < 1024) ? a[i] : ((i < 2048) ? b[i - 1024] : c[i - 2048]);
}

// ---------------- residual init: out[r][c] = x[r][c] + bias[c] ----------------
__global__ __launch_bounds__(256) void init_resid(const float* __restrict__ x,
    const float* __restrict__ bias, float* __restrict__ out) {
  int i = blockIdx.x * 256 + threadIdx.x;       // float4 index
  float4 v = ((const float4*)x)[i];
  float4 b = ((const float4*)bias)[i & 255];    // 1024/4 float4 per row
  v.x += b.x; v.y += b.y; v.z += b.z; v.w += b.w;
  ((float4*)out)[i] = v;
}

// ---------------- transpose + convert to bf16 ----------------
template <typename TIN>
__global__ __launch_bounds__(256) void transpose_cvt(const TIN* __restrict__ in,
    ushort* __restrict__ out, int ldin, int ldout,
    long inZhi, long inZlo, long outZ) {
  int z = blockIdx.z;
  in  += (long)(z >> 4) * inZhi + (long)(z & 15) * inZlo;
  out += (long)z * outZ;
  __shared__ float tile[32][33];
  int c0 = blockIdx.x * 32, r0 = blockIdx.y * 32;
  int tx = threadIdx.x, ty = threadIdx.y;
  for (int i = ty; i < 32; i += 8)
    tile[i][tx] = ld_as_float(in, (long)(r0 + i) * ldin + c0 + tx);
  __syncthreads();
  for (int i = ty; i < 32; i += 8)
    out[(long)(c0 + i) * ldout + r0 + tx] = f2bf(tile[tx][i]);
}

// ---------------- bf16 MFMA GEMM, 2-deep pipelined, T2-swizzled LDS ----------------
template <int ACT, bool BIAS, bool RES, typename TOUT, bool ATOMIC = false>
__global__ __launch_bounds__(256) void gemm_bt(
    const ushort* __restrict__ A, const ushort* __restrict__ BT, TOUT* __restrict__ C,
    const float* __restrict__ bias, const float* __restrict__ resp,
    int M, int K, int lda, int ldb, int ldc,
    long aZhi, long aZlo, long bZhi, long bZlo, long cZhi, long cZlo) {
  __shared__ __align__(16) ushort lA[2][128 * 64];
  __shared__ __align__(16) ushort lB[2][128 * 64];
  int z = blockIdx.z;
  A  += (long)(z >> 4) * aZhi + (long)(z & 15) * aZlo;
  BT += (long)(z >> 4) * bZhi + (long)(z & 15) * bZlo;
  long coff = (long)(z >> 4) * cZhi + (long)(z & 15) * cZlo;
  int gx = gridDim.x;
  int nwg = gx * gridDim.y;
  int lin = blockIdx.x + gx * blockIdx.y;
  int wg = (lin & 7) * (nwg >> 3) + (lin >> 3);
  int n0 = (wg / gx) * 128, m0 = (wg % gx) * 128;
  int tid = threadIdx.x, lane = tid & 63, wid = tid >> 6;
  int wr = wid >> 1, wc = wid & 1;
  int lrow = lane >> 3;                       // 0..7 (row within 8-row chunk)
  int swz = ((lane & 7) ^ lrow) << 3;         // pre-swizzled global k-offset (elements)
  int Mm1 = M - 1;
  f32x4 acc[4][4];
#pragma unroll
  for (int i = 0; i < 4; i++)
#pragma unroll
    for (int j = 0; j < 4; j++) acc[i][j] = (f32x4){0.f, 0.f, 0.f, 0.f};

  auto STAGE = [&](int kt, int buf) {
    const ushort* Ak = A + (kt << 6) + swz;
    const ushort* Bk = BT + (kt << 6) + swz;
#pragma unroll
    for (int c = 0; c < 4; ++c) {
      int ch = (wid << 2) | c;          // chunk 0..15 (8 rows each)
      int rb = (ch << 3) + lrow;        // row 0..127
      gld_lds16(Ak + (long)(n0 + rb) * lda, &lA[buf][ch << 9]);
      int mrow = min(m0 + rb, Mm1);
      gld_lds16(Bk + (long)mrow * ldb, &lB[buf][ch << 9]);
    }
  };

  int nK = K >> 6;
  STAGE(0, 0);
  for (int kt = 0; kt < nK; ++kt) {
    int cur = kt & 1;
    if (kt + 1 < nK) {
      STAGE(kt + 1, cur ^ 1);
      asm volatile("s_waitcnt vmcnt(8)" ::: "memory");
    } else {
      asm volatile("s_waitcnt vmcnt(0)" ::: "memory");
    }
    __builtin_amdgcn_s_barrier();
    __builtin_amdgcn_sched_barrier(0);
#pragma unroll
    for (int kk = 0; kk < 2; ++kk) {
      int g = (kk << 2) | (lane >> 4);
      int kfs = ((g ^ (lane & 7)) << 3);
      bf16x8 af[4], bfr[4];
#pragma unroll
      for (int i = 0; i < 4; i++) {
        af[i]  = *(const bf16x8*)(&lA[cur][((wr << 6) + (i << 4) + (lane & 15)) * 64 + kfs]);
        bfr[i] = *(const bf16x8*)(&lB[cur][((wc << 6) + (i << 4) + (lane & 15)) * 64 + kfs]);
      }
#pragma unroll
      for (int i = 0; i < 4; i++)
#pragma unroll
        for (int j = 0; j < 4; j++)
          acc[i][j] = __builtin_amdgcn_mfma_f32_16x16x32_bf16(af[i], bfr[j], acc[i][j], 0, 0, 0);
    }
    asm volatile("s_waitcnt lgkmcnt(0)" ::: "memory");
    __builtin_amdgcn_s_barrier();
    __builtin_amdgcn_sched_barrier(0);
  }
#pragma unroll
  for (int i = 0; i < 4; i++) {
    int rbase = n0 + wr * 64 + i * 16 + ((lane >> 4) << 2);
#pragma unroll
    for (int j = 0; j < 4; j++) {
      int col = m0 + wc * 64 + j * 16 + (lane & 15);
      if (col < M) {
        float bv = (BIAS && (!ATOMIC || z == 0)) ? bias[col] : 0.0f;
#pragma unroll
        for (int q = 0; q < 4; q++) {
          int rowg = rbase + q;
          float vv = acc[i][j][q] + bv;
          if (ACT == 1) vv = 0.5f * vv * (1.0f + erff(vv * 0.70710678118f));
          long idx = coff + (long)rowg * ldc + col;
          if constexpr (ATOMIC) {
            atomic_add_f32((float*)&C[idx], vv);
          } else {
            if (RES) vv += resp[idx];
            st_out(C, idx, vv);
          }
        }
      }
    }
  }
}

// ---------------- fused flash attention ----------------
// One block = one (b,h) x one 64-row Q tile. Loop over 8 K/V tiles of 128.
// qkv: [4096][3072] bf16 (q|k|v). vt: [bh][64 hd][1024 s] bf16. attn out: [4096][1024] bf16.
// Layouts: A/B frag row|col = lane&15, k-grp = lane>>4 (+4*step); C/D col=lane&15,
// row=(lane>>4)*4+q. LDS tiles use the gemm staging XOR (slot s of row r holds global
// group s^(r&7)); P uses idx ^= (row&7)<<3 on write AND read (same involution).
#define QBLK 64
#define KBLK 128
__global__ __launch_bounds__(256) void flash_attn(
    const ushort* __restrict__ qkv, const ushort* __restrict__ vt,
    ushort* __restrict__ attn) {
  __shared__ __align__(16) ushort lP[QBLK * 128];   // 16KB; Q staged here first
  __shared__ __align__(16) ushort lK[KBLK * 64];    // 16KB [k][hd]
  __shared__ __align__(16) ushort lV[64 * KBLK];    // 16KB [hd][k]
  __shared__ float mrun[QBLK], lrun[QBLK], salpha[QBLK], part[2][QBLK];

  int qt = blockIdx.x, bh = blockIdx.z;
  int b = bh >> 4, hh = bh & 15;
  int tid = threadIdx.x, lane = tid & 63, wid = tid >> 6;
  int lo = lane & 15, hi = lane >> 4;
  int wr = wid >> 1, wc = wid & 1;
  int lrow = lane >> 3;
  int swz8 = ((lane & 7) ^ lrow) << 3;     // staging swizzle for [*][64] tiles

  const ushort* Qg = qkv + (long)(b * 1024 + qt * QBLK) * 3072 + hh * 64;
  const ushort* Kg = qkv + (long)(b * 1024) * 3072 + 1024 + hh * 64;
  const ushort* Vg = vt + (long)bh * 64 * 1024;

  // ---- stage Q [64][64] into lP ----
#pragma unroll
  for (int c = 0; c < 2; ++c) {
    int ch = wid * 2 + c;
    int rb = ch * 8 + lrow;
    gld_lds16(Qg + (long)rb * 3072 + swz8, &lP[ch << 9]);
  }
  __syncthreads();
  bf16x8 a_q[2][2];
#pragma unroll
  for (int kk = 0; kk < 2; ++kk)
#pragma unroll
    for (int i = 0; i < 2; ++i)
      a_q[kk][i] = *(const bf16x8*)&lP[(wr * 32 + i * 16 + lo) * 64 +
                                       (((kk * 4 + hi) ^ (lane & 7)) << 3)];
  if (tid < QBLK) { mrun[tid] = -1e30f; lrun[tid] = 0.0f; }
  __syncthreads();   // Q frags extracted; lP free for P

  f32x4 acc_o[4];
#pragma unroll
  for (int j = 0; j < 4; ++j) acc_o[j] = (f32x4){0.f, 0.f, 0.f, 0.f};

  for (int t = 0; t < 8; ++t) {
    // stage K tile [128][64]
#pragma unroll
    for (int c = 0; c < 4; ++c) {
      int ch = (wid << 2) | c;
      int rb = (ch << 3) + lrow;
      gld_lds16(Kg + (long)(t * KBLK + rb) * 3072 + swz8, &lK[ch << 9]);
    }
    // stage V^T tile [64 hd][128 k]
#pragma unroll
    for (int c = 0; c < 4; ++c) {
      int ch = (wid << 2) | c;
      int hd = (ch << 2) + hi;
      gld_lds16(Vg + (long)hd * 1024 + t * KBLK + ((lo ^ (hd & 7)) << 3), &lV[ch << 9]);
    }
    __syncthreads();   // vmcnt(0) drain + barrier

    // ---- QK^T: acc_s[i][j], rows wr*32+i*16, cols wc*64+j*16 ----
    f32x4 acc_s[2][4];
#pragma unroll
    for (int i = 0; i < 2; ++i)
#pragma unroll
      for (int j = 0; j < 4; ++j) acc_s[i][j] = (f32x4){0.f, 0.f, 0.f, 0.f};
#pragma unroll
    for (int kk = 0; kk < 2; ++kk) {
      bf16x8 bk[4];
#pragma unroll
      for (int j = 0; j < 4; ++j)
        bk[j] = *(const bf16x8*)&lK[(wc * 64 + j * 16 + lo) * 64 +
                                    (((kk * 4 + hi) ^ (lane & 7)) << 3)];
#pragma unroll
      for (int i = 0; i < 2; ++i)
#pragma unroll
        for (int j = 0; j < 4; ++j)
          acc_s[i][j] = __builtin_amdgcn_mfma_f32_16x16x32_bf16(a_q[kk][i], bk[j], acc_s[i][j], 0, 0, 0);
    }
    // scale 1/sqrt(64)
#pragma unroll
    for (int i = 0; i < 2; ++i)
#pragma unroll
      for (int j = 0; j < 4; ++j)
#pragma unroll
        for (int q = 0; q < 4; ++q) acc_s[i][j][q] *= 0.125f;

    // ---- partial row max over this wave's 64 cols ----
    float pmx[2][4];
#pragma unroll
    for (int i = 0; i < 2; ++i)
#pragma unroll
      for (int q = 0; q < 4; ++q) {
        float m = fmaxf(fmaxf(acc_s[i][0][q], acc_s[i][1][q]),
                        fmaxf(acc_s[i][2][q], acc_s[i][3][q]));
#pragma unroll
        for (int off = 1; off < 16; off <<= 1) m = fmaxf(m, __shfl_xor(m, off));
        pmx[i][q] = m;
        if (lo == i * 4 + q) part[wc][wr * 32 + i * 16 + hi * 4 + q] = m;
      }
    __syncthreads();
    if (tid < QBLK) {
      float mnew = fmaxf(mrun[tid], fmaxf(part[0][tid], part[1][tid]));
      salpha[tid] = __expf(mrun[tid] - mnew);
      mrun[tid] = mnew;
    }
    __syncthreads();

    // ---- exp, P->LDS (bf16, swizzled), partial row sum ----
#pragma unroll
    for (int i = 0; i < 2; ++i)
#pragma unroll
      for (int q = 0; q < 4; ++q) {
        int row = wr * 32 + i * 16 + hi * 4 + q;
        float mn = mrun[row];
        float s = 0.f;
#pragma unroll
        for (int j = 0; j < 4; ++j) {
          float e = __expf(acc_s[i][j][q] - mn);
          s += e;
          int col = wc * 64 + j * 16 + lo;
          lP[(row * 128 + col) ^ ((row & 7) << 3)] = f2bf(e);
        }
#pragma unroll
        for (int off = 1; off < 16; off <<= 1) s += __shfl_xor(s, off);
        if (lo == i * 4 + q) part[wc][row] = s;
        (void)pmx[i][q];
      }
    __syncthreads();
    if (tid < QBLK) lrun[tid] = lrun[tid] * salpha[tid] + part[0][tid] + part[1][tid];

    // ---- PV: wave owns q rows wid*16..+15, all 64 hd; contraction 128 ----
    float al[4];
#pragma unroll
    for (int q = 0; q < 4; ++q) al[q] = salpha[wid * 16 + hi * 4 + q];
#pragma unroll
    for (int j = 0; j < 4; ++j)
#pragma unroll
      for (int q = 0; q < 4; ++q) acc_o[j][q] *= al[q];
#pragma unroll
    for (int ks = 0; ks < 4; ++ks) {
      bf16x8 ap = *(const bf16x8*)&lP[((wid * 16 + lo) * 128) +
                                      ((((ks * 4 + hi) ^ (lo & 7)) << 3))];
      bf16x8 bv[4];
#pragma unroll
      for (int j = 0; j < 4; ++j)
        bv[j] = *(const bf16x8*)&lV[(j * 16 + lo) * 128 +
                                    (((ks * 4 + hi) ^ (lo & 7)) << 3)];
#pragma unroll
      for (int j = 0; j < 4; ++j)
        acc_o[j] = __builtin_amdgcn_mfma_f32_16x16x32_bf16(ap, bv[j], acc_o[j], 0, 0, 0);
    }
    __syncthreads();   // lP/lK/lV/salpha consumed; safe for next tile
  }

  // ---- epilogue: O /= l, write bf16 ----
  float linv[4];
#pragma unroll
  for (int q = 0; q < 4; ++q) linv[q] = 1.0f / lrun[wid * 16 + hi * 4 + q];
#pragma unroll
  for (int j = 0; j < 4; ++j)
#pragma unroll
    for (int q = 0; q < 4; ++q) {
      int qrow = qt * QBLK + wid * 16 + hi * 4 + q;
      attn[(long)(b * 1024 + qrow) * 1024 + hh * 64 + j * 16 + lo] = f2bf(acc_o[j][q] * linv[q]);
    }
}

// ---------------- host orchestration ----------------
extern "C" void kernel_launch(void* const* d_in, const int* in_sizes, int n_in,
                              void* d_out, int out_size, void* d_ws, size_t ws_size,
                              hipStream_t stream) {
  const float* x    = (const float*)d_in[0];
  const float* wq   = (const float*)d_in[1];
  const float* bq   = (const float*)d_in[2];
  const float* wk   = (const float*)d_in[3];
  const float* bk   = (const float*)d_in[4];
  const float* wv   = (const float*)d_in[5];
  const float* bv   = (const float*)d_in[6];
  const float* wo   = (const float*)d_in[7];
  const float* bo   = (const float*)d_in[8];
  const float* w1   = (const float*)d_in[9];
  const float* b1   = (const float*)d_in[10];
  const float* w2   = (const float*)d_in[11];
  const float* b2   = (const float*)d_in[12];
  const float* ln1g = (const float*)d_in[13];
  const float* ln1b = (const float*)d_in[14];
  const float* ln2g = (const float*)d_in[15];
  const float* ln2b = (const float*)d_in[16];
  float* out = (float*)d_out;

  char* ws = (char*)d_ws;
  size_t off = 0;
  auto alloc = [&](size_t bytes) { void* p = ws + off; off += (bytes + 255) & ~(size_t)255; return p; };
  ushort* h     = (ushort*)alloc((size_t)NTOK * DMODEL * 2);        // 8MB
  ushort* wqkvT = (ushort*)alloc((size_t)3 * DMODEL * DMODEL * 2);  // 6MB
  ushort* woT   = (ushort*)alloc((size_t)DMODEL * DMODEL * 2);      // 2MB
  float*  bqkv  = (float*)alloc((size_t)3 * DMODEL * 4);            // 12KB
  ushort* qkv   = (ushort*)alloc((size_t)NTOK * 3 * DMODEL * 2);    // 24MB
  ushort* vt    = (ushort*)alloc((size_t)64 * HDIM * S_LEN * 2);    // 8MB [bh][hd][s]
  ushort* attn  = (ushort*)alloc((size_t)NTOK * DMODEL * 2);        // 8MB
  ushort* w1T   = (ushort*)alloc((size_t)DMODEL * FFDIM * 2);       // 8MB [FF][D]
  ushort* w2T   = (ushort*)alloc((size_t)FFDIM * DMODEL * 2);       // 8MB [D][FF]
  ushort* gact  = (ushort*)alloc((size_t)NTOK * FFDIM * 2);         // 32MB

  dim3 tb32(32, 8);
  hipLaunchKernelGGL((transpose_cvt<float>), dim3(DMODEL/32, DMODEL/32, 1), tb32, 0, stream,
                     wq, wqkvT, DMODEL, DMODEL, 0, 0, 0);
  hipLaunchKernelGGL((transpose_cvt<float>), dim3(DMODEL/32, DMODEL/32, 1), tb32, 0, stream,
                     wk, wqkvT + (size_t)DMODEL * DMODEL, DMODEL, DMODEL, 0, 0, 0);
  hipLaunchKernelGGL((transpose_cvt<float>), dim3(DMODEL/32, DMODEL/32, 1), tb32, 0, stream,
                     wv, wqkvT + (size_t)2 * DMODEL * DMODEL, DMODEL, DMODEL, 0, 0, 0);
  hipLaunchKernelGGL((transpose_cvt<float>), dim3(DMODEL/32, DMODEL/32, 1), tb32, 0, stream,
                     wo, woT, DMODEL, DMODEL, 0, 0, 0);
  hipLaunchKernelGGL(concat3, dim3(12), dim3(256), 0, stream, bq, bk, bv, bqkv);

  // LN1
  hipLaunchKernelGGL(ln_kernel, dim3(NTOK), dim3(256), 0, stream, x, ln1g, ln1b, h);

  // merged QKV GEMM
  hipLaunchKernelGGL((gemm_bt<0, true, false, ushort>), dim3(24, 32, 1), dim3(256), 0, stream,
                     h, wqkvT, qkv, bqkv, (const float*)nullptr,
                     3 * DMODEL, DMODEL, DMODEL, DMODEL, 3 * DMODEL, 0L, 0L, 0L, 0L, 0L, 0L);

  // V transpose per (b,h): qkv[:, 2048 + h*64 ..] -> vt [bh][hd][s]
  hipLaunchKernelGGL((transpose_cvt<ushort>), dim3(HDIM/32, S_LEN/32, 64), tb32, 0, stream,
                     qkv + 2 * DMODEL, vt, 3 * DMODEL, S_LEN,
                     (long)S_LEN * 3 * DMODEL, 64L, (long)HDIM * S_LEN);

  // fused flash attention: 16 q-tiles x 64 (b,h)
  hipLaunchKernelGGL(flash_attn, dim3(16, 1, 64), dim3(256), 0, stream, qkv, vt, attn);

  // out = x + bo, then out += attn @ wo (split-K=2, atomic)
  hipLaunchKernelGGL(init_resid, dim3(4096), dim3(256), 0, stream, x, bo, out);
  hipLaunchKernelGGL((gemm_bt<0, false, false, float, true>), dim3(8, 32, 2), dim3(256), 0, stream,
                     attn, woT, out, (const float*)nullptr, (const float*)nullptr,
                     DMODEL, 512, DMODEL, DMODEL, DMODEL,
                     0L, 512L, 0L, 512L, 0L, 0L);
  // LN2
  hipLaunchKernelGGL(ln_kernel, dim3(NTOK), dim3(256), 0, stream, out, ln2g, ln2b, h);
  // FFN weight transposes
  hipLaunchKernelGGL((transpose_cvt<float>), dim3(FFDIM/32, DMODEL/32, 1), tb32, 0, stream,
                     w1, w1T, FFDIM, DMODEL, 0, 0, 0);
  hipLaunchKernelGGL((transpose_cvt<float>), dim3(DMODEL/32, FFDIM/32, 1), tb32, 0, stream,
                     w2, w2T, DMODEL, FFDIM, 0, 0, 0);
  // FFN1: gelu(h @ w1 + b1) -> gact
  hipLaunchKernelGGL((gemm_bt<1, true, false, ushort>), dim3(32, 32, 1), dim3(256), 0, stream,
                     h, w1T, gact, b1, (const float*)nullptr,
                     FFDIM, DMODEL, DMODEL, DMODEL, FFDIM, 0L, 0L, 0L, 0L, 0L, 0L);
  // FFN2: out += gact @ w2 + b2 (split-K=2, atomic)
  hipLaunchKernelGGL((gemm_bt<0, true, false, float, true>), dim3(8, 32, 2), dim3(256), 0, stream,
                     gact, w2T, out, b2, (const float*)nullptr,
                     DMODEL, 2048, FFDIM, FFDIM, DMODEL,
                     0L, 2048L, 0L, 2048L, 0L, 0L);
  (void)in_sizes; (void)n_in; (void)out_size; (void)ws_size;
}

// Round 6
// 311.081 us; speedup vs baseline: 1.9763x; 1.0874x over previous
//
#include <hip/hip_runtime.h>
#include <hip/hip_bf16.h>
#include <cstdint>

// ---- problem constants ----
#define S_LEN  1024
#define DMODEL 1024
#define NTOK   4096   // B*S = 4*1024
#define NHEAD  16
#define HDIM   64
#define FFDIM  4096
#define NBATCH 4

using bf16x8 = __attribute__((ext_vector_type(8))) short;
using f32x4  = __attribute__((ext_vector_type(4))) float;

__device__ __forceinline__ ushort f2bf(float f) {
  union { float f; uint32_t u; } a; a.f = f;
  uint32_t u = a.u;
  u += 0x7FFFu + ((u >> 16) & 1u);   // RNE
  return (ushort)(u >> 16);
}
__device__ __forceinline__ float bf2f(ushort u) {
  union { uint32_t u; float f; } c; c.u = ((uint32_t)u) << 16; return c.f;
}
__device__ __forceinline__ float ld_as_float(const float* p, long i) { return p[i]; }
__device__ __forceinline__ float ld_as_float(const ushort* p, long i) { return bf2f(p[i]); }
__device__ __forceinline__ void st_out(float* C, long i, float v) { C[i] = v; }
__device__ __forceinline__ void st_out(ushort* C, long i, float v) { C[i] = f2bf(v); }

// async global->LDS, 16B per lane; LDS dest = wave-uniform base + lane*16 (linear!)
__device__ __forceinline__ void gld_lds16(const void* g, void* l) {
  __builtin_amdgcn_global_load_lds((const __attribute__((address_space(1))) void*)g,
                                   (__attribute__((address_space(3))) void*)l, 16, 0, 0);
}
// hardware f32 atomic add (no return)
__device__ __forceinline__ void atomic_add_f32(float* p, float v) {
  asm volatile("global_atomic_add_f32 %0, %1, off" :: "v"(p), "v"(v) : "memory");
}

// ---------------- LayerNorm (row of 1024 f32) -> bf16 ----------------
__global__ __launch_bounds__(256) void ln_kernel(const float* __restrict__ x,
    const float* __restrict__ g, const float* __restrict__ b,
    ushort* __restrict__ out) {
  int row = blockIdx.x;
  int tid = threadIdx.x;
  const float4* xr = (const float4*)(x + (long)row * DMODEL);
  float4 v = xr[tid];
  float s  = v.x + v.y + v.z + v.w;
  float s2 = v.x*v.x + v.y*v.y + v.z*v.z + v.w*v.w;
  for (int off = 32; off; off >>= 1) { s += __shfl_down(s, off); s2 += __shfl_down(s2, off); }
  __shared__ float red[8];
  int wid = tid >> 6, lane = tid & 63;
  if (lane == 0) { red[wid] = s; red[wid + 4] = s2; }
  __syncthreads();
  if (tid == 0) {
    red[0] = red[0] + red[1] + red[2] + red[3];
    red[4] = red[4] + red[5] + red[6] + red[7];
  }
  __syncthreads();
  float mu  = red[0] * (1.0f / DMODEL);
  float var = red[4] * (1.0f / DMODEL) - mu * mu;
  float rs  = rsqrtf(var + 1e-5f);
  float4 gg = ((const float4*)g)[tid];
  float4 bb = ((const float4*)b)[tid];
  ushort4 o;
  o.x = f2bf((v.x - mu) * rs * gg.x + bb.x);
  o.y = f2bf((v.y - mu) * rs * gg.y + bb.y);
  o.z = f2bf((v.z - mu) * rs * gg.z + bb.z);
  o.w = f2bf((v.w - mu) * rs * gg.w + bb.w);
  ((ushort4*)(out + (long)row * DMODEL))[tid] = o;
}

// ---------------- bias concat: [bq|bk|bv] -> 3072 floats ----------------
__global__ __launch_bounds__(256) void concat3(const float* __restrict__ a,
    const float* __restrict__ b, const float* __restrict__ c, float* __restrict__ o) {
  int i = blockIdx.x * 256 + threadIdx.x;
  o[i] = (i < 1024) ? a[i] : ((i < 2048) ? b[i - 1024] : c[i - 2048]);
}

// ---------------- residual init: out[r][c] = x[r][c] + bias[c] ----------------
__global__ __launch_bounds__(256) void init_resid(const float* __restrict__ x,
    const float* __restrict__ bias, float* __restrict__ out) {
  int i = blockIdx.x * 256 + threadIdx.x;       // float4 index
  float4 v = ((const float4*)x)[i];
  float4 b = ((const float4*)bias)[i & 255];    // 1024/4 float4 per row
  v.x += b.x; v.y += b.y; v.z += b.z; v.w += b.w;
  ((float4*)out)[i] = v;
}

// ---------------- transpose + convert to bf16 ----------------
template <typename TIN>
__global__ __launch_bounds__(256) void transpose_cvt(const TIN* __restrict__ in,
    ushort* __restrict__ out, int ldin, int ldout,
    long inZhi, long inZlo, long outZ) {
  int z = blockIdx.z;
  in  += (long)(z >> 4) * inZhi + (long)(z & 15) * inZlo;
  out += (long)z * outZ;
  __shared__ float tile[32][33];
  int c0 = blockIdx.x * 32, r0 = blockIdx.y * 32;
  int tx = threadIdx.x, ty = threadIdx.y;
  for (int i = ty; i < 32; i += 8)
    tile[i][tx] = ld_as_float(in, (long)(r0 + i) * ldin + c0 + tx);
  __syncthreads();
  for (int i = ty; i < 32; i += 8)
    out[(long)(c0 + i) * ldout + r0 + tx] = f2bf(tile[tx][i]);
}

// ---------------- bf16 MFMA GEMM, 2-deep pipelined, T2-swizzled LDS ----------------
template <int ACT, bool BIAS, bool RES, typename TOUT, bool ATOMIC = false>
__global__ __launch_bounds__(256) void gemm_bt(
    const ushort* __restrict__ A, const ushort* __restrict__ BT, TOUT* __restrict__ C,
    const float* __restrict__ bias, const float* __restrict__ resp,
    int M, int K, int lda, int ldb, int ldc,
    long aZhi, long aZlo, long bZhi, long bZlo, long cZhi, long cZlo) {
  __shared__ __align__(16) ushort lA[2][128 * 64];
  __shared__ __align__(16) ushort lB[2][128 * 64];
  int z = blockIdx.z;
  A  += (long)(z >> 4) * aZhi + (long)(z & 15) * aZlo;
  BT += (long)(z >> 4) * bZhi + (long)(z & 15) * bZlo;
  long coff = (long)(z >> 4) * cZhi + (long)(z & 15) * cZlo;
  int gx = gridDim.x;
  int nwg = gx * gridDim.y;
  int lin = blockIdx.x + gx * blockIdx.y;
  int wg = (lin & 7) * (nwg >> 3) + (lin >> 3);
  int n0 = (wg / gx) * 128, m0 = (wg % gx) * 128;
  int tid = threadIdx.x, lane = tid & 63, wid = tid >> 6;
  int wr = wid >> 1, wc = wid & 1;
  int lrow = lane >> 3;                       // 0..7 (row within 8-row chunk)
  int swz = ((lane & 7) ^ lrow) << 3;         // pre-swizzled global k-offset (elements)
  int Mm1 = M - 1;
  f32x4 acc[4][4];
#pragma unroll
  for (int i = 0; i < 4; i++)
#pragma unroll
    for (int j = 0; j < 4; j++) acc[i][j] = (f32x4){0.f, 0.f, 0.f, 0.f};

  auto STAGE = [&](int kt, int buf) {
    const ushort* Ak = A + (kt << 6) + swz;
    const ushort* Bk = BT + (kt << 6) + swz;
#pragma unroll
    for (int c = 0; c < 4; ++c) {
      int ch = (wid << 2) | c;          // chunk 0..15 (8 rows each)
      int rb = (ch << 3) + lrow;        // row 0..127
      gld_lds16(Ak + (long)(n0 + rb) * lda, &lA[buf][ch << 9]);
      int mrow = min(m0 + rb, Mm1);
      gld_lds16(Bk + (long)mrow * ldb, &lB[buf][ch << 9]);
    }
  };

  int nK = K >> 6;
  STAGE(0, 0);
  for (int kt = 0; kt < nK; ++kt) {
    int cur = kt & 1;
    if (kt + 1 < nK) {
      STAGE(kt + 1, cur ^ 1);
      asm volatile("s_waitcnt vmcnt(8)" ::: "memory");
    } else {
      asm volatile("s_waitcnt vmcnt(0)" ::: "memory");
    }
    __builtin_amdgcn_s_barrier();
    __builtin_amdgcn_sched_barrier(0);
#pragma unroll
    for (int kk = 0; kk < 2; ++kk) {
      int g = (kk << 2) | (lane >> 4);
      int kfs = ((g ^ (lane & 7)) << 3);
      bf16x8 af[4], bfr[4];
#pragma unroll
      for (int i = 0; i < 4; i++) {
        af[i]  = *(const bf16x8*)(&lA[cur][((wr << 6) + (i << 4) + (lane & 15)) * 64 + kfs]);
        bfr[i] = *(const bf16x8*)(&lB[cur][((wc << 6) + (i << 4) + (lane & 15)) * 64 + kfs]);
      }
#pragma unroll
      for (int i = 0; i < 4; i++)
#pragma unroll
        for (int j = 0; j < 4; j++)
          acc[i][j] = __builtin_amdgcn_mfma_f32_16x16x32_bf16(af[i], bfr[j], acc[i][j], 0, 0, 0);
    }
    asm volatile("s_waitcnt lgkmcnt(0)" ::: "memory");
    __builtin_amdgcn_s_barrier();
    __builtin_amdgcn_sched_barrier(0);
  }
#pragma unroll
  for (int i = 0; i < 4; i++) {
    int rbase = n0 + wr * 64 + i * 16 + ((lane >> 4) << 2);
#pragma unroll
    for (int j = 0; j < 4; j++) {
      int col = m0 + wc * 64 + j * 16 + (lane & 15);
      if (col < M) {
        float bv = (BIAS && (!ATOMIC || z == 0)) ? bias[col] : 0.0f;
#pragma unroll
        for (int q = 0; q < 4; q++) {
          int rowg = rbase + q;
          float vv = acc[i][j][q] + bv;
          if (ACT == 1) vv = 0.5f * vv * (1.0f + erff(vv * 0.70710678118f));
          long idx = coff + (long)rowg * ldc + col;
          if constexpr (ATOMIC) {
            atomic_add_f32((float*)&C[idx], vv);
          } else {
            if (RES) vv += resp[idx];
            st_out(C, idx, vv);
          }
        }
      }
    }
  }
}

// ---------------- fused flash attention (wave-owns-rows, 2 barriers/tile) ----------------
// One block = one (b,h) x 64 q-rows; 4 waves x 16 q-rows each; each wave computes the FULL
// 128-wide K-strip so softmax stats are per-wave (16-lane shuffles + registers, no LDS).
// K/V double-buffered with counted vmcnt (gemm_bt pattern). P lives in wave-private LDS
// (16x128) with the measured conflict-free involution: write col^((row&7)<<3), read
// slot g^(row&7). Layouts: A/B row|col=lane&15, k-grp=lane>>4 (+4/step); C/D col=lane&15,
// row=(lane>>4)*4+q (m89/m91-verified).
#define QBLK 64
#define KBLK 128
__global__ __launch_bounds__(256) void flash_attn(
    const ushort* __restrict__ qkv, const ushort* __restrict__ vt,
    ushort* __restrict__ attn) {
  __shared__ __align__(16) ushort lK[2][KBLK * 64];    // 16KB x2  [k][hd]
  __shared__ __align__(16) ushort lV[2][64 * KBLK];    // 16KB x2  [hd][k]
  __shared__ __align__(16) ushort lP[4 * 16 * KBLK];   // 16KB: per-wave 16x128 (Q staged here first)

  int qt = blockIdx.x, bh = blockIdx.z;
  int b = bh >> 4, hh = bh & 15;
  int tid = threadIdx.x, lane = tid & 63, wid = tid >> 6;
  int lo = lane & 15, hi = lane >> 4;
  int lrow = lane >> 3;
  int swz8 = ((lane & 7) ^ lrow) << 3;     // staging swizzle for [*][64] row-major tiles

  const ushort* Qg = qkv + (long)(b * 1024 + qt * QBLK) * 3072 + hh * 64;
  const ushort* Kg = qkv + (long)(b * 1024) * 3072 + 1024 + hh * 64;
  const ushort* Vg = vt + (long)bh * 64 * 1024;
  ushort* lPw = lP + wid * (16 * KBLK);    // wave-private P

  auto STAGE = [&](int t, int buf) {
#pragma unroll
    for (int c = 0; c < 4; ++c) {          // K tile [128][64]
      int ch = (wid << 2) | c;
      int rb = (ch << 3) + lrow;
      gld_lds16(Kg + (long)(t * KBLK + rb) * 3072 + swz8, &lK[buf][ch << 9]);
    }
#pragma unroll
    for (int c = 0; c < 4; ++c) {          // V^T tile [64 hd][128 k]
      int ch = (wid << 2) | c;
      int hd = (ch << 2) + hi;
      gld_lds16(Vg + (long)hd * 1024 + t * KBLK + ((lo ^ (hd & 7)) << 3), &lV[buf][ch << 9]);
    }
  };

  // ---- prologue: stage Q [64][64] into lP (wave-local chunks), then tile 0 ----
#pragma unroll
  for (int c = 0; c < 2; ++c) {
    int ch = wid * 2 + c;                  // rows wid*16 .. wid*16+15
    int rb = ch * 8 + lrow;
    gld_lds16(Qg + (long)rb * 3072 + swz8, &lP[ch << 9]);
  }
  STAGE(0, 0);                             // outstanding: 2(Q) + 8(t0)
  asm volatile("s_waitcnt vmcnt(8)" ::: "memory");   // Q retired
  __builtin_amdgcn_sched_barrier(0);
  bf16x8 a_q[2];                           // wave's 16 q-rows, k=0..63
#pragma unroll
  for (int kk = 0; kk < 2; ++kk)
    a_q[kk] = *(const bf16x8*)&lP[(wid * 16 + lo) * 64 + (((kk * 4 + hi) ^ (lo & 7)) << 3)];
  asm volatile("s_waitcnt lgkmcnt(0)" ::: "memory");  // Q in regs
  __builtin_amdgcn_sched_barrier(0);
  __builtin_amdgcn_s_barrier();            // all waves extracted Q; lP free for P

  float m_run[4], l_run[4];
#pragma unroll
  for (int q = 0; q < 4; ++q) { m_run[q] = -1e30f; l_run[q] = 0.0f; }
  f32x4 acc_o[4];
#pragma unroll
  for (int j = 0; j < 4; ++j) acc_o[j] = (f32x4){0.f, 0.f, 0.f, 0.f};

  for (int t = 0; t < 8; ++t) {
    int cur = t & 1;
    if (t + 1 < 8) {
      STAGE(t + 1, cur ^ 1);
      asm volatile("s_waitcnt vmcnt(8)" ::: "memory");   // cur tile's 8 retired
    } else {
      asm volatile("s_waitcnt vmcnt(0)" ::: "memory");
    }
    __builtin_amdgcn_s_barrier();
    __builtin_amdgcn_sched_barrier(0);

    // ---- QK^T: wave's 16 rows x full 128 cols ----
    f32x4 s[8];
#pragma unroll
    for (int j = 0; j < 8; ++j) s[j] = (f32x4){0.f, 0.f, 0.f, 0.f};
#pragma unroll
    for (int kk = 0; kk < 2; ++kk) {
      int slot = ((kk * 4 + hi) ^ (lo & 7)) << 3;
#pragma unroll
      for (int j = 0; j < 8; ++j) {
        bf16x8 bk = *(const bf16x8*)&lK[cur][(j * 16 + lo) * 64 + slot];
        s[j] = __builtin_amdgcn_mfma_f32_16x16x32_bf16(a_q[kk], bk, s[j], 0, 0, 0);
      }
    }
#pragma unroll
    for (int j = 0; j < 8; ++j)
#pragma unroll
      for (int q = 0; q < 4; ++q) s[j][q] *= 0.125f;

    // ---- per-wave online softmax (16-lane shuffles, register stats) ----
    float alpha[4];
#pragma unroll
    for (int q = 0; q < 4; ++q) {
      float m = fmaxf(fmaxf(fmaxf(s[0][q], s[1][q]), fmaxf(s[2][q], s[3][q])),
                      fmaxf(fmaxf(s[4][q], s[5][q]), fmaxf(s[6][q], s[7][q])));
#pragma unroll
      for (int off = 1; off < 16; off <<= 1) m = fmaxf(m, __shfl_xor(m, off));
      float mnew = fmaxf(m_run[q], m);
      alpha[q] = __expf(m_run[q] - mnew);
      m_run[q] = mnew;
    }
    float psum[4] = {0.f, 0.f, 0.f, 0.f};
#pragma unroll
    for (int j = 0; j < 8; ++j)
#pragma unroll
      for (int q = 0; q < 4; ++q) {
        float e = __expf(s[j][q] - m_run[q]);
        psum[q] += e;
        int row = hi * 4 + q;
        int col = j * 16 + lo;
        lPw[row * KBLK + (col ^ ((row & 7) << 3))] = f2bf(e);
      }
#pragma unroll
    for (int q = 0; q < 4; ++q) {
#pragma unroll
      for (int off = 1; off < 16; off <<= 1) psum[q] += __shfl_xor(psum[q], off);
      l_run[q] = l_run[q] * alpha[q] + psum[q];
    }

    // ---- PV: O[16 x 64] += P[16 x 128] @ V[128 x 64] (wave-private P) ----
#pragma unroll
    for (int j = 0; j < 4; ++j)
#pragma unroll
      for (int q = 0; q < 4; ++q) acc_o[j][q] *= alpha[q];
#pragma unroll
    for (int ks = 0; ks < 4; ++ks) {
      int slot = ((ks * 4 + hi) ^ (lo & 7)) << 3;
      bf16x8 ap = *(const bf16x8*)&lPw[lo * KBLK + slot];
#pragma unroll
      for (int j = 0; j < 4; ++j) {
        bf16x8 bv = *(const bf16x8*)&lV[cur][(j * 16 + lo) * KBLK + slot];
        acc_o[j] = __builtin_amdgcn_mfma_f32_16x16x32_bf16(ap, bv, acc_o[j], 0, 0, 0);
      }
    }
    asm volatile("s_waitcnt lgkmcnt(0)" ::: "memory");  // cur K/V (and P) reads retired
    __builtin_amdgcn_s_barrier();
    __builtin_amdgcn_sched_barrier(0);
  }

  // ---- epilogue: O /= l, write bf16 ----
#pragma unroll
  for (int q = 0; q < 4; ++q) {
    float linv = 1.0f / l_run[q];
    int qrow = qt * QBLK + wid * 16 + hi * 4 + q;
#pragma unroll
    for (int j = 0; j < 4; ++j)
      attn[(long)(b * 1024 + qrow) * 1024 + hh * 64 + j * 16 + lo] = f2bf(acc_o[j][q] * linv);
  }
}

// ---------------- host orchestration ----------------
extern "C" void kernel_launch(void* const* d_in, const int* in_sizes, int n_in,
                              void* d_out, int out_size, void* d_ws, size_t ws_size,
                              hipStream_t stream) {
  const float* x    = (const float*)d_in[0];
  const float* wq   = (const float*)d_in[1];
  const float* bq   = (const float*)d_in[2];
  const float* wk   = (const float*)d_in[3];
  const float* bk   = (const float*)d_in[4];
  const float* wv   = (const float*)d_in[5];
  const float* bv   = (const float*)d_in[6];
  const float* wo   = (const float*)d_in[7];
  const float* bo   = (const float*)d_in[8];
  const float* w1   = (const float*)d_in[9];
  const float* b1   = (const float*)d_in[10];
  const float* w2   = (const float*)d_in[11];
  const float* b2   = (const float*)d_in[12];
  const float* ln1g = (const float*)d_in[13];
  const float* ln1b = (const float*)d_in[14];
  const float* ln2g = (const float*)d_in[15];
  const float* ln2b = (const float*)d_in[16];
  float* out = (float*)d_out;

  char* ws = (char*)d_ws;
  size_t off = 0;
  auto alloc = [&](size_t bytes) { void* p = ws + off; off += (bytes + 255) & ~(size_t)255; return p; };
  ushort* h     = (ushort*)alloc((size_t)NTOK * DMODEL * 2);        // 8MB
  ushort* wqkvT = (ushort*)alloc((size_t)3 * DMODEL * DMODEL * 2);  // 6MB
  ushort* woT   = (ushort*)alloc((size_t)DMODEL * DMODEL * 2);      // 2MB
  float*  bqkv  = (float*)alloc((size_t)3 * DMODEL * 4);            // 12KB
  ushort* qkv   = (ushort*)alloc((size_t)NTOK * 3 * DMODEL * 2);    // 24MB
  ushort* vt    = (ushort*)alloc((size_t)64 * HDIM * S_LEN * 2);    // 8MB [bh][hd][s]
  ushort* attn  = (ushort*)alloc((size_t)NTOK * DMODEL * 2);        // 8MB
  ushort* w1T   = (ushort*)alloc((size_t)DMODEL * FFDIM * 2);       // 8MB [FF][D]
  ushort* w2T   = (ushort*)alloc((size_t)FFDIM * DMODEL * 2);       // 8MB [D][FF]
  ushort* gact  = (ushort*)alloc((size_t)NTOK * FFDIM * 2);         // 32MB

  dim3 tb32(32, 8);
  hipLaunchKernelGGL((transpose_cvt<float>), dim3(DMODEL/32, DMODEL/32, 1), tb32, 0, stream,
                     wq, wqkvT, DMODEL, DMODEL, 0, 0, 0);
  hipLaunchKernelGGL((transpose_cvt<float>), dim3(DMODEL/32, DMODEL/32, 1), tb32, 0, stream,
                     wk, wqkvT + (size_t)DMODEL * DMODEL, DMODEL, DMODEL, 0, 0, 0);
  hipLaunchKernelGGL((transpose_cvt<float>), dim3(DMODEL/32, DMODEL/32, 1), tb32, 0, stream,
                     wv, wqkvT + (size_t)2 * DMODEL * DMODEL, DMODEL, DMODEL, 0, 0, 0);
  hipLaunchKernelGGL((transpose_cvt<float>), dim3(DMODEL/32, DMODEL/32, 1), tb32, 0, stream,
                     wo, woT, DMODEL, DMODEL, 0, 0, 0);
  hipLaunchKernelGGL(concat3, dim3(12), dim3(256), 0, stream, bq, bk, bv, bqkv);

  // LN1
  hipLaunchKernelGGL(ln_kernel, dim3(NTOK), dim3(256), 0, stream, x, ln1g, ln1b, h);

  // merged QKV GEMM
  hipLaunchKernelGGL((gemm_bt<0, true, false, ushort>), dim3(24, 32, 1), dim3(256), 0, stream,
                     h, wqkvT, qkv, bqkv, (const float*)nullptr,
                     3 * DMODEL, DMODEL, DMODEL, DMODEL, 3 * DMODEL, 0L, 0L, 0L, 0L, 0L, 0L);

  // V transpose per (b,h): qkv[:, 2048 + h*64 ..] -> vt [bh][hd][s]
  hipLaunchKernelGGL((transpose_cvt<ushort>), dim3(HDIM/32, S_LEN/32, 64), tb32, 0, stream,
                     qkv + 2 * DMODEL, vt, 3 * DMODEL, S_LEN,
                     (long)S_LEN * 3 * DMODEL, 64L, (long)HDIM * S_LEN);

  // fused flash attention: 16 q-tiles x 64 (b,h)
  hipLaunchKernelGGL(flash_attn, dim3(16, 1, 64), dim3(256), 0, stream, qkv, vt, attn);

  // out = x + bo, then out += attn @ wo (split-K=2, atomic)
  hipLaunchKernelGGL(init_resid, dim3(4096), dim3(256), 0, stream, x, bo, out);
  hipLaunchKernelGGL((gemm_bt<0, false, false, float, true>), dim3(8, 32, 2), dim3(256), 0, stream,
                     attn, woT, out, (const float*)nullptr, (const float*)nullptr,
                     DMODEL, 512, DMODEL, DMODEL, DMODEL,
                     0L, 512L, 0L, 512L, 0L, 0L);
  // LN2
  hipLaunchKernelGGL(ln_kernel, dim3(NTOK), dim3(256), 0, stream, out, ln2g, ln2b, h);
  // FFN weight transposes
  hipLaunchKernelGGL((transpose_cvt<float>), dim3(FFDIM/32, DMODEL/32, 1), tb32, 0, stream,
                     w1, w1T, FFDIM, DMODEL, 0, 0, 0);
  hipLaunchKernelGGL((transpose_cvt<float>), dim3(DMODEL/32, FFDIM/32, 1), tb32, 0, stream,
                     w2, w2T, DMODEL, FFDIM, 0, 0, 0);
  // FFN1: gelu(h @ w1 + b1) -> gact
  hipLaunchKernelGGL((gemm_bt<1, true, false, ushort>), dim3(32, 32, 1), dim3(256), 0, stream,
                     h, w1T, gact, b1, (const float*)nullptr,
                     FFDIM, DMODEL, DMODEL, DMODEL, FFDIM, 0L, 0L, 0L, 0L, 0L, 0L);
  // FFN2: out += gact @ w2 + b2 (split-K=2, atomic)
  hipLaunchKernelGGL((gemm_bt<0, true, false, float, true>), dim3(8, 32, 2), dim3(256), 0, stream,
                     gact, w2T, out, b2, (const float*)nullptr,
                     DMODEL, 2048, FFDIM, FFDIM, DMODEL,
                     0L, 2048L, 0L, 2048L, 0L, 0L);
  (void)in_sizes; (void)n_in; (void)out_size; (void)ws_size;
}